// Round 2
// baseline (8584.109 us; speedup 1.0000x reference)
//
#include <hip/hip_runtime.h>
#include <hip/hip_bf16.h>
#include <math.h>

#define B     8
#define S     512
#define MEM   512
#define L     4
#define E     512
#define H     8
#define DH    64
#define OBS   128
#define KLEN  1024   // MEM + S

__device__ __forceinline__ float gelu_tanh(float x) {
    return 0.5f * x * (1.0f + tanhf(0.7978845608028654f * (x + 0.044715f * x * x * x)));
}

// ---------------- positional embedding: pe[p, j] -----------------------------
__global__ __launch_bounds__(256) void pe_kernel(float* __restrict__ pe) {
    const int idx = blockIdx.x * 256 + threadIdx.x;
    const int p = idx >> 9;        // row (E=512)
    const int j = idx & 511;
    const float pos = (float)(KLEN - p);       // pos_seq = [K, K-1, ..., 1]
    const int m = (j < 256) ? j : (j - 256);
    const float invf = expf(-(float)(2 * m) * (9.210340371976184f / (float)E));
    const float a = pos * invf;
    pe[idx] = (j < 256) ? sinf(a) : cosf(a);
}

// ---------------- generic tiled GEMM: C[M,N] = act(A@Bw + bias) + res --------
// A: [M, lda] fp32, Bw: [Kd, N] row-major fp32, C fp32.
__global__ __launch_bounds__(256) void gemm_kernel(
    const float* __restrict__ A, int lda,
    const float* __restrict__ Bw,
    const float* __restrict__ bias,  // [N] or null
    const float* __restrict__ res,   // [M,N] or null (added after act)
    float* __restrict__ C,
    int M, int N, int Kd, int act)   // act: 0 none, 1 gelu
{
    __shared__ __align__(16) float As[16][64];
    __shared__ __align__(16) float Bs[16][64];
    const int tid = threadIdx.x;
    const int m0 = blockIdx.y * 64, n0 = blockIdx.x * 64;
    const int tx = tid & 15, ty = tid >> 4;
    const int ar = tid >> 2, ac = (tid & 3) << 2;   // A tile: 64 rows x 16 k
    const int br = tid >> 4, bc = (tid & 15) << 2;  // B tile: 16 k x 64 cols
    float acc[4][4] = {};
    for (int k0 = 0; k0 < Kd; k0 += 16) {
        const float4 av4 = *(const float4*)(A + (size_t)(m0 + ar) * lda + k0 + ac);
        As[ac + 0][ar] = av4.x; As[ac + 1][ar] = av4.y;
        As[ac + 2][ar] = av4.z; As[ac + 3][ar] = av4.w;
        *(float4*)&Bs[br][bc] = *(const float4*)(Bw + (size_t)(k0 + br) * N + n0 + bc);
        __syncthreads();
        #pragma unroll
        for (int kk = 0; kk < 16; ++kk) {
            const float4 a = *(const float4*)&As[kk][ty << 2];
            const float4 bb = *(const float4*)&Bs[kk][tx << 2];
            const float av[4] = {a.x, a.y, a.z, a.w};
            const float bv[4] = {bb.x, bb.y, bb.z, bb.w};
            #pragma unroll
            for (int i = 0; i < 4; ++i)
                #pragma unroll
                for (int j = 0; j < 4; ++j)
                    acc[i][j] = fmaf(av[i], bv[j], acc[i][j]);
        }
        __syncthreads();
    }
    #pragma unroll
    for (int i = 0; i < 4; ++i) {
        const int m = m0 + (ty << 2) + i;
        #pragma unroll
        for (int j = 0; j < 4; ++j) {
            const int n = n0 + (tx << 2) + j;
            float v = acc[i][j];
            if (bias) v += bias[n];
            if (act) v = gelu_tanh(v);
            if (res) v += res[(size_t)m * N + n];
            C[(size_t)m * N + n] = v;
        }
    }
}

// ---------------- LayerNorm over E=512, one block per row --------------------
// memories source: row rr = b*MEM+kp -> vk[b*KLEN + kp]
__global__ __launch_bounds__(256) void ln_mem_kernel(
    const float* __restrict__ mem, int li,
    const float* __restrict__ gam, const float* __restrict__ bet,
    float* __restrict__ vkdst)
{
    const int rr = blockIdx.x;
    const int t = threadIdx.x;
    const float* sp = mem + ((size_t)rr * L + li) * E;
    const float x0 = sp[t], x1 = sp[t + 256];
    float s = x0 + x1, ss = fmaf(x0, x0, x1 * x1);
    #pragma unroll
    for (int off = 32; off; off >>= 1) { s += __shfl_down(s, off, 64); ss += __shfl_down(ss, off, 64); }
    __shared__ float tmp[8];
    const int wid = t >> 6, lane = t & 63;
    if (!lane) { tmp[wid] = s; tmp[4 + wid] = ss; }
    __syncthreads();
    s = tmp[0] + tmp[1] + tmp[2] + tmp[3];
    ss = tmp[4] + tmp[5] + tmp[6] + tmp[7];
    const float mean = s * (1.0f / E);
    const float var = ss * (1.0f / E) - mean * mean;
    const float rstd = rsqrtf(var + 1e-6f);
    const int b = rr >> 9, kp = rr & 511;  // MEM = 512
    float* dst = vkdst + ((size_t)b * KLEN + kp) * E;
    dst[t]       = (x0 - mean) * rstd * gam[t] + bet[t];
    dst[t + 256] = (x1 - mean) * rstd * gam[t + 256] + bet[t + 256];
}

// fp32 source: row rr -> dst1[rr*E]; optionally also vk[b*KLEN + MEM + s]
__global__ __launch_bounds__(256) void ln_f32_kernel(
    const float* __restrict__ src,
    const float* __restrict__ gam, const float* __restrict__ bet,
    float* __restrict__ dst1, float* __restrict__ vkdst)
{
    const int rr = blockIdx.x;
    const int t = threadIdx.x;
    const float* sp = src + (size_t)rr * E;
    const float x0 = sp[t], x1 = sp[t + 256];
    float s = x0 + x1, ss = fmaf(x0, x0, x1 * x1);
    #pragma unroll
    for (int off = 32; off; off >>= 1) { s += __shfl_down(s, off, 64); ss += __shfl_down(ss, off, 64); }
    __shared__ float tmp[8];
    const int wid = t >> 6, lane = t & 63;
    if (!lane) { tmp[wid] = s; tmp[4 + wid] = ss; }
    __syncthreads();
    s = tmp[0] + tmp[1] + tmp[2] + tmp[3];
    ss = tmp[4] + tmp[5] + tmp[6] + tmp[7];
    const float mean = s * (1.0f / E);
    const float var = ss * (1.0f / E) - mean * mean;
    const float rstd = rsqrtf(var + 1e-6f);
    const float y0 = (x0 - mean) * rstd * gam[t] + bet[t];
    const float y1 = (x1 - mean) * rstd * gam[t + 256] + bet[t + 256];
    dst1[(size_t)rr * E + t] = y0;
    dst1[(size_t)rr * E + t + 256] = y1;
    if (vkdst) {
        const int b = rr >> 9, spos = rr & 511;   // S = 512
        float* d2 = vkdst + ((size_t)b * KLEN + MEM + spos) * E;
        d2[t] = y0; d2[t + 256] = y1;
    }
}

// ---------------- attention: one block per (b, h, qpos) ----------------------
// scores[k] = ((q+u)·k[k] + (q+v)·r[k + S-1 - qpos]) * 1/8 for k <= MEM+qpos
__global__ __launch_bounds__(256) void attn_kernel(
    const float* __restrict__ Q,   // [B*S, E]  (h*DH+d cols)
    const float* __restrict__ Kb,  // [B*KLEN, E]
    const float* __restrict__ Vb,  // [B*KLEN, E]
    const float* __restrict__ Rb,  // [KLEN, E]
    const float* __restrict__ ub,  // [H*DH] layer slice
    const float* __restrict__ vbias,// [H*DH] layer slice
    float* __restrict__ O)         // [B*S, E]
{
    const int blk = blockIdx.x;
    const int qpos = blk & (S - 1);
    const int bh = blk >> 9;
    const int h = bh & (H - 1);
    const int b = bh >> 3;
    const int tid = threadIdx.x;

    __shared__ __align__(16) float qu[DH];
    __shared__ __align__(16) float qv[DH];
    __shared__ float sc[KLEN];
    __shared__ float tmp[8];
    __shared__ float op[4][DH];

    if (tid < DH) {
        const float qq = Q[((size_t)(b * S + qpos)) * E + h * DH + tid];
        qu[tid] = qq + ub[h * DH + tid];
        qv[tid] = qq + vbias[h * DH + tid];
    }
    __syncthreads();

    const int kmax = MEM + qpos;   // inclusive
    float sv[4];
    #pragma unroll
    for (int t = 0; t < 4; ++t) {
        const int kk = tid + t * 256;
        float sres = -1e30f;
        if (kk <= kmax) {
            const float* kp = Kb + ((size_t)(b * KLEN + kk)) * E + h * DH;
            const float* rp = Rb + ((size_t)(kk + (S - 1) - qpos)) * E + h * DH;
            float acck = 0.f, accr = 0.f;
            #pragma unroll 4
            for (int d = 0; d < DH; d += 4) {
                const float4 kv = *(const float4*)(kp + d);
                const float4 rv = *(const float4*)(rp + d);
                const float4 quv = *(const float4*)(&qu[d]);
                const float4 qvv = *(const float4*)(&qv[d]);
                acck = fmaf(quv.x, kv.x, acck); accr = fmaf(qvv.x, rv.x, accr);
                acck = fmaf(quv.y, kv.y, acck); accr = fmaf(qvv.y, rv.y, accr);
                acck = fmaf(quv.z, kv.z, acck); accr = fmaf(qvv.z, rv.z, accr);
                acck = fmaf(quv.w, kv.w, acck); accr = fmaf(qvv.w, rv.w, accr);
            }
            sres = (acck + accr) * 0.125f;   // 1/sqrt(DH)
        }
        sv[t] = sres;
    }

    // block max
    float mx = fmaxf(fmaxf(sv[0], sv[1]), fmaxf(sv[2], sv[3]));
    #pragma unroll
    for (int off = 32; off; off >>= 1) mx = fmaxf(mx, __shfl_down(mx, off, 64));
    const int wid = tid >> 6, lane = tid & 63;
    if (!lane) tmp[wid] = mx;
    __syncthreads();
    mx = fmaxf(fmaxf(tmp[0], tmp[1]), fmaxf(tmp[2], tmp[3]));

    // exp + sum (unnormalized probs stay in sc; fold 1/sum into the output)
    float ls = 0.f;
    #pragma unroll
    for (int t = 0; t < 4; ++t) {
        const int kk = tid + t * 256;
        const float e = (kk <= kmax) ? expf(sv[t] - mx) : 0.f;
        sc[kk] = e;
        ls += e;
    }
    #pragma unroll
    for (int off = 32; off; off >>= 1) ls += __shfl_down(ls, off, 64);
    if (!lane) tmp[4 + wid] = ls;
    __syncthreads();
    const float inv = 1.0f / (tmp[4] + tmp[5] + tmp[6] + tmp[7]);

    // o[d] = sum_k p[k] * v[k, d]
    const int d = tid & 63, g = tid >> 6;
    float accv = 0.f;
    for (int kk = g; kk <= kmax; kk += 4) {
        accv = fmaf(sc[kk], Vb[((size_t)(b * KLEN + kk)) * E + h * DH + d], accv);
    }
    op[g][d] = accv;
    __syncthreads();
    if (tid < DH) {
        O[((size_t)(b * S + qpos)) * E + h * DH + tid] =
            (op[0][tid] + op[1][tid] + op[2][tid] + op[3][tid]) * inv;
    }
}

extern "C" void kernel_launch(void* const* d_in, const int* in_sizes, int n_in,
                              void* d_out, int out_size, void* d_ws, size_t ws_size,
                              hipStream_t stream)
{
    const float* obs  = (const float*)d_in[0];
    const float* mem  = (const float*)d_in[1];
    // d_in[2] = mask: deterministic (k <= MEM + q), recomputed in-kernel
    const float* Wenc = (const float*)d_in[3];
    const float* benc = (const float*)d_in[4];
    const float* ln1s = (const float*)d_in[5];
    const float* ln1b = (const float*)d_in[6];
    const float* Wq   = (const float*)d_in[7];
    const float* bq   = (const float*)d_in[8];
    const float* Wk   = (const float*)d_in[9];
    const float* bk   = (const float*)d_in[10];
    const float* Wv   = (const float*)d_in[11];
    const float* bv   = (const float*)d_in[12];
    const float* Wr   = (const float*)d_in[13];
    const float* ub   = (const float*)d_in[14];
    const float* vb   = (const float*)d_in[15];
    const float* Wo   = (const float*)d_in[16];
    const float* bo   = (const float*)d_in[17];
    const float* ln2s = (const float*)d_in[18];
    const float* ln2b = (const float*)d_in[19];
    const float* W1   = (const float*)d_in[20];
    const float* b1   = (const float*)d_in[21];
    const float* W2   = (const float*)d_in[22];
    const float* b2   = (const float*)d_in[23];

    float* ws = (float*)d_ws;
    size_t off = 0;
    float* X  = ws + off; off += (size_t)B * S * E;      // 2M
    float* PE = ws + off; off += (size_t)KLEN * E;       // 0.5M
    float* VK = ws + off; off += (size_t)B * KLEN * E;   // 4M  (reused as FF1)
    float* KB = ws + off; off += (size_t)B * KLEN * E;   // 4M
    float* VB = ws + off; off += (size_t)B * KLEN * E;   // 4M
    float* QN = ws + off; off += (size_t)B * S * E;      // 2M  (qn / hn)
    float* QB = ws + off; off += (size_t)B * S * E;      // 2M
    float* RB = ws + off; off += (size_t)KLEN * E;       // 0.5M
    float* OB = ws + off; off += (size_t)B * S * E;      // 2M
    float* HB = ws + off; off += (size_t)B * S * E;      // 2M
    float* FF = VK;                                      // reuse (vk dead by then)

    pe_kernel<<<(KLEN * E) / 256, 256, 0, stream>>>(PE);
    // encoder: x = obs @ W_enc + b_enc
    gemm_kernel<<<dim3(E / 64, (B * S) / 64), 256, 0, stream>>>(
        obs, OBS, Wenc, benc, nullptr, X, B * S, E, OBS, 0);

    for (int li = 0; li < L; ++li) {
        const size_t wOff = (size_t)li * E * E;
        const size_t vOff = (size_t)li * E;   // E == H*DH

        ln_mem_kernel<<<B * MEM, 256, 0, stream>>>(mem, li, ln1s + vOff, ln1b + vOff, VK);
        ln_f32_kernel<<<B * S, 256, 0, stream>>>(X, ln1s + vOff, ln1b + vOff, QN, VK);

        gemm_kernel<<<dim3(E / 64, (B * S) / 64), 256, 0, stream>>>(
            QN, E, Wq + wOff, bq + vOff, nullptr, QB, B * S, E, E, 0);
        gemm_kernel<<<dim3(E / 64, (B * KLEN) / 64), 256, 0, stream>>>(
            VK, E, Wk + wOff, bk + vOff, nullptr, KB, B * KLEN, E, E, 0);
        gemm_kernel<<<dim3(E / 64, (B * KLEN) / 64), 256, 0, stream>>>(
            VK, E, Wv + wOff, bv + vOff, nullptr, VB, B * KLEN, E, E, 0);
        gemm_kernel<<<dim3(E / 64, KLEN / 64), 256, 0, stream>>>(
            PE, E, Wr + wOff, nullptr, nullptr, RB, KLEN, E, E, 0);

        attn_kernel<<<B * H * S, 256, 0, stream>>>(QB, KB, VB, RB, ub + vOff, vb + vOff, OB);

        // h = x + (o @ Wo + bo)
        gemm_kernel<<<dim3(E / 64, (B * S) / 64), 256, 0, stream>>>(
            OB, E, Wo + wOff, bo + vOff, X, HB, B * S, E, E, 0);
        // hn = ln2(h)
        ln_f32_kernel<<<B * S, 256, 0, stream>>>(HB, ln2s + vOff, ln2b + vOff, QN, nullptr);
        // ff1 = gelu(hn @ W1 + b1)
        gemm_kernel<<<dim3(E / 64, (B * S) / 64), 256, 0, stream>>>(
            QN, E, W1 + wOff, b1 + vOff, nullptr, FF, B * S, E, E, 1);
        // x = ff1 @ W2 + b2 + h
        gemm_kernel<<<dim3(E / 64, (B * S) / 64), 256, 0, stream>>>(
            FF, E, W2 + wOff, b2 + vOff, HB, X, B * S, E, E, 0);
    }

    // final copy fp32 -> output
    hipMemcpyAsync(d_out, X, (size_t)B * S * E * sizeof(float),
                   hipMemcpyDeviceToDevice, stream);
}

// Round 3
// 2818.986 us; speedup vs baseline: 3.0451x; 3.0451x over previous
//
#include <hip/hip_runtime.h>
#include <hip/hip_bf16.h>
#include <math.h>

#define B     8
#define S     512
#define MEM   512
#define L     4
#define E     512
#define H     8
#define DH    64
#define OBS   128
#define KLEN  1024   // MEM + S
#define QC    32     // q rows per attention block
#define KT    32     // k cols per attention tile

__device__ __forceinline__ float gelu_tanh(float x) {
    return 0.5f * x * (1.0f + tanhf(0.7978845608028654f * (x + 0.044715f * x * x * x)));
}

// ---------------- positional embedding: pe[p, j] -----------------------------
__global__ __launch_bounds__(256) void pe_kernel(float* __restrict__ pe) {
    const int idx = blockIdx.x * 256 + threadIdx.x;
    const int p = idx >> 9;        // row (E=512)
    const int j = idx & 511;
    const float pos = (float)(KLEN - p);       // pos_seq = [K, K-1, ..., 1]
    const int m = (j < 256) ? j : (j - 256);
    const float invf = expf(-(float)(2 * m) * (9.210340371976184f / (float)E));
    const float a = pos * invf;
    pe[idx] = (j < 256) ? sinf(a) : cosf(a);
}

// ---------------- generic tiled GEMM: C[M,N] = act(A@Bw + bias) + res --------
__global__ __launch_bounds__(256) void gemm_kernel(
    const float* __restrict__ A, int lda,
    const float* __restrict__ Bw,
    const float* __restrict__ bias,  // [N] or null
    const float* __restrict__ res,   // [M,N] or null (added after act)
    float* __restrict__ C,
    int M, int N, int Kd, int act)   // act: 0 none, 1 gelu
{
    __shared__ __align__(16) float As[16][64];
    __shared__ __align__(16) float Bs[16][64];
    const int tid = threadIdx.x;
    const int m0 = blockIdx.y * 64, n0 = blockIdx.x * 64;
    const int tx = tid & 15, ty = tid >> 4;
    const int ar = tid >> 2, ac = (tid & 3) << 2;
    const int br = tid >> 4, bc = (tid & 15) << 2;
    float acc[4][4] = {};
    for (int k0 = 0; k0 < Kd; k0 += 16) {
        const float4 av4 = *(const float4*)(A + (size_t)(m0 + ar) * lda + k0 + ac);
        As[ac + 0][ar] = av4.x; As[ac + 1][ar] = av4.y;
        As[ac + 2][ar] = av4.z; As[ac + 3][ar] = av4.w;
        *(float4*)&Bs[br][bc] = *(const float4*)(Bw + (size_t)(k0 + br) * N + n0 + bc);
        __syncthreads();
        #pragma unroll
        for (int kk = 0; kk < 16; ++kk) {
            const float4 a = *(const float4*)&As[kk][ty << 2];
            const float4 bb = *(const float4*)&Bs[kk][tx << 2];
            const float av[4] = {a.x, a.y, a.z, a.w};
            const float bv[4] = {bb.x, bb.y, bb.z, bb.w};
            #pragma unroll
            for (int i = 0; i < 4; ++i)
                #pragma unroll
                for (int j = 0; j < 4; ++j)
                    acc[i][j] = fmaf(av[i], bv[j], acc[i][j]);
        }
        __syncthreads();
    }
    #pragma unroll
    for (int i = 0; i < 4; ++i) {
        const int m = m0 + (ty << 2) + i;
        #pragma unroll
        for (int j = 0; j < 4; ++j) {
            const int n = n0 + (tx << 2) + j;
            float v = acc[i][j];
            if (bias) v += bias[n];
            if (act) v = gelu_tanh(v);
            if (res) v += res[(size_t)m * N + n];
            C[(size_t)m * N + n] = v;
        }
    }
}

// ---------------- LayerNorm over E=512, one block per row --------------------
__global__ __launch_bounds__(256) void ln_mem_kernel(
    const float* __restrict__ mem, int li,
    const float* __restrict__ gam, const float* __restrict__ bet,
    float* __restrict__ vkdst)
{
    const int rr = blockIdx.x;
    const int t = threadIdx.x;
    const float* sp = mem + ((size_t)rr * L + li) * E;
    const float x0 = sp[t], x1 = sp[t + 256];
    float s = x0 + x1, ss = fmaf(x0, x0, x1 * x1);
    #pragma unroll
    for (int off = 32; off; off >>= 1) { s += __shfl_down(s, off, 64); ss += __shfl_down(ss, off, 64); }
    __shared__ float tmp[8];
    const int wid = t >> 6, lane = t & 63;
    if (!lane) { tmp[wid] = s; tmp[4 + wid] = ss; }
    __syncthreads();
    s = tmp[0] + tmp[1] + tmp[2] + tmp[3];
    ss = tmp[4] + tmp[5] + tmp[6] + tmp[7];
    const float mean = s * (1.0f / E);
    const float var = ss * (1.0f / E) - mean * mean;
    const float rstd = rsqrtf(var + 1e-6f);
    const int b = rr >> 9, kp = rr & 511;  // MEM = 512
    float* dst = vkdst + ((size_t)b * KLEN + kp) * E;
    dst[t]       = (x0 - mean) * rstd * gam[t] + bet[t];
    dst[t + 256] = (x1 - mean) * rstd * gam[t + 256] + bet[t + 256];
}

__global__ __launch_bounds__(256) void ln_f32_kernel(
    const float* __restrict__ src,
    const float* __restrict__ gam, const float* __restrict__ bet,
    float* __restrict__ dst1, float* __restrict__ vkdst)
{
    const int rr = blockIdx.x;
    const int t = threadIdx.x;
    const float* sp = src + (size_t)rr * E;
    const float x0 = sp[t], x1 = sp[t + 256];
    float s = x0 + x1, ss = fmaf(x0, x0, x1 * x1);
    #pragma unroll
    for (int off = 32; off; off >>= 1) { s += __shfl_down(s, off, 64); ss += __shfl_down(ss, off, 64); }
    __shared__ float tmp[8];
    const int wid = t >> 6, lane = t & 63;
    if (!lane) { tmp[wid] = s; tmp[4 + wid] = ss; }
    __syncthreads();
    s = tmp[0] + tmp[1] + tmp[2] + tmp[3];
    ss = tmp[4] + tmp[5] + tmp[6] + tmp[7];
    const float mean = s * (1.0f / E);
    const float var = ss * (1.0f / E) - mean * mean;
    const float rstd = rsqrtf(var + 1e-6f);
    const float y0 = (x0 - mean) * rstd * gam[t] + bet[t];
    const float y1 = (x1 - mean) * rstd * gam[t + 256] + bet[t + 256];
    dst1[(size_t)rr * E + t] = y0;
    dst1[(size_t)rr * E + t + 256] = y1;
    if (vkdst) {
        const int b = rr >> 9, spos = rr & 511;   // S = 512
        float* d2 = vkdst + ((size_t)b * KLEN + MEM + spos) * E;
        d2[t] = y0; d2[t + 256] = y1;
    }
}

// ---------------- fused flash attention --------------------------------------
// block = (qc, h, b): 32 q-rows, online softmax over k-tiles of 32.
// scores[q,k] = ((q+u)·K[k] + (q+v)·R[k+S-1-q]) * 0.125, mask k <= MEM+q.
__global__ __launch_bounds__(256) void flash_attn_kernel(
    const float* __restrict__ Q,   // [B*S, E]
    const float* __restrict__ Kb,  // [B*KLEN, E]
    const float* __restrict__ Vb,  // [B*KLEN, E]
    const float* __restrict__ Rb,  // [KLEN, E]
    const float* __restrict__ ub,  // [H*DH] layer slice
    const float* __restrict__ vbias,
    float* __restrict__ O)         // [B*S, E]
{
    const int qc = blockIdx.x, h = blockIdx.y, b = blockIdx.z;
    const int q0 = qc * QC;
    const int t = threadIdx.x;
    const int qp = t >> 4, kp = t & 15;          // 16x16 thread grid
    const int qq0 = 2 * qp, qq1 = qq0 + 1;       // 2 q-rows per thread
    const int kl0 = kp, kl1 = kp + 16;           // 2 k-cols per thread (strided)

    __shared__ __align__(16) float Qu[QC][68];
    __shared__ __align__(16) float Qv[QC][68];
    __shared__ __align__(16) float Ks[KT][68];
    __shared__ __align__(16) float Rs[KT + QC][68];   // diagonal band, 64 rows
    __shared__ __align__(16) float Vs[KT][68];
    __shared__ __align__(16) float Ps[QC][36];

    // ---- stage Qu/Qv ----
    {
        const int qq = t >> 3, dq = (t & 7) * 8;
        const float* qrow = Q + ((size_t)(b * S + q0 + qq)) * E + h * DH;
        const float4 a0 = *(const float4*)(qrow + dq);
        const float4 a1 = *(const float4*)(qrow + dq + 4);
        const float4 u0 = *(const float4*)(ub + h * DH + dq);
        const float4 u1 = *(const float4*)(ub + h * DH + dq + 4);
        const float4 v0 = *(const float4*)(vbias + h * DH + dq);
        const float4 v1 = *(const float4*)(vbias + h * DH + dq + 4);
        *(float4*)&Qu[qq][dq]     = make_float4(a0.x+u0.x, a0.y+u0.y, a0.z+u0.z, a0.w+u0.w);
        *(float4*)&Qu[qq][dq+4]   = make_float4(a1.x+u1.x, a1.y+u1.y, a1.z+u1.z, a1.w+u1.w);
        *(float4*)&Qv[qq][dq]     = make_float4(a0.x+v0.x, a0.y+v0.y, a0.z+v0.z, a0.w+v0.w);
        *(float4*)&Qv[qq][dq+4]   = make_float4(a1.x+v1.x, a1.y+v1.y, a1.z+v1.z, a1.w+v1.w);
    }

    float o0[4] = {0.f, 0.f, 0.f, 0.f};
    float o1[4] = {0.f, 0.f, 0.f, 0.f};
    float m0 = -3.0e38f, m1 = -3.0e38f, l0 = 0.f, l1 = 0.f;

    const int ntiles = ((MEM + q0 + QC - 1) >> 5) + 1;   // covers k <= MEM+q0+31
    const int r00 = kp - 2 * qp + (QC - 1);              // R band row for (qq0,kl0)

    for (int kt = 0; kt < ntiles; ++kt) {
        const int k0 = kt * KT;
        __syncthreads();   // previous tile's consumers done
        // ---- stage K, V tiles (rows k0..k0+31 always < KLEN) ----
        {
            const int kk = t >> 3, dq = (t & 7) * 8;
            const float* kr = Kb + ((size_t)(b * KLEN + k0 + kk)) * E + h * DH;
            const float* vr = Vb + ((size_t)(b * KLEN + k0 + kk)) * E + h * DH;
            *(float4*)&Ks[kk][dq]     = *(const float4*)(kr + dq);
            *(float4*)&Ks[kk][dq + 4] = *(const float4*)(kr + dq + 4);
            *(float4*)&Vs[kk][dq]     = *(const float4*)(vr + dq);
            *(float4*)&Vs[kk][dq + 4] = *(const float4*)(vr + dq + 4);
        }
        // ---- stage R band: global rows rbase..rbase+63, clamped ----
        {
            const int rbase = k0 + (S - 1) - q0 - (QC - 1);   // k0 + 480 - q0 (>= 0)
            const int rr = t >> 2, dq = (t & 3) * 16;
            int j = rbase + rr; if (j > KLEN - 1) j = KLEN - 1;  // clamped rows feed masked scores only
            const float* rrow = Rb + (size_t)j * E + h * DH;
            *(float4*)&Rs[rr][dq]      = *(const float4*)(rrow + dq);
            *(float4*)&Rs[rr][dq + 4]  = *(const float4*)(rrow + dq + 4);
            *(float4*)&Rs[rr][dq + 8]  = *(const float4*)(rrow + dq + 8);
            *(float4*)&Rs[rr][dq + 12] = *(const float4*)(rrow + dq + 12);
        }
        __syncthreads();

        // ---- scores (2q x 2k per thread) ----
        float s00 = 0.f, s01 = 0.f, s10 = 0.f, s11 = 0.f;
        #pragma unroll
        for (int d = 0; d < DH; d += 4) {
            const float4 a0 = *(const float4*)&Qu[qq0][d];
            const float4 a1 = *(const float4*)&Qu[qq1][d];
            const float4 c0 = *(const float4*)&Qv[qq0][d];
            const float4 c1 = *(const float4*)&Qv[qq1][d];
            const float4 k0v = *(const float4*)&Ks[kl0][d];
            const float4 k1v = *(const float4*)&Ks[kl1][d];
            const float4 rA = *(const float4*)&Rs[r00][d];        // (qq0,kl0)
            const float4 rB = *(const float4*)&Rs[r00 - 1][d];    // (qq1,kl0)
            const float4 rC = *(const float4*)&Rs[r00 + 16][d];   // (qq0,kl1)
            const float4 rD = *(const float4*)&Rs[r00 + 15][d];   // (qq1,kl1)
            s00 = fmaf(a0.x,k0v.x,fmaf(a0.y,k0v.y,fmaf(a0.z,k0v.z,fmaf(a0.w,k0v.w,s00))));
            s00 = fmaf(c0.x,rA.x, fmaf(c0.y,rA.y, fmaf(c0.z,rA.z, fmaf(c0.w,rA.w, s00))));
            s01 = fmaf(a0.x,k1v.x,fmaf(a0.y,k1v.y,fmaf(a0.z,k1v.z,fmaf(a0.w,k1v.w,s01))));
            s01 = fmaf(c0.x,rC.x, fmaf(c0.y,rC.y, fmaf(c0.z,rC.z, fmaf(c0.w,rC.w, s01))));
            s10 = fmaf(a1.x,k0v.x,fmaf(a1.y,k0v.y,fmaf(a1.z,k0v.z,fmaf(a1.w,k0v.w,s10))));
            s10 = fmaf(c1.x,rB.x, fmaf(c1.y,rB.y, fmaf(c1.z,rB.z, fmaf(c1.w,rB.w, s10))));
            s11 = fmaf(a1.x,k1v.x,fmaf(a1.y,k1v.y,fmaf(a1.z,k1v.z,fmaf(a1.w,k1v.w,s11))));
            s11 = fmaf(c1.x,rD.x, fmaf(c1.y,rD.y, fmaf(c1.z,rD.z, fmaf(c1.w,rD.w, s11))));
        }
        // scale + mask (k <= MEM + q)
        s00 = (k0 + kl0 <= MEM + q0 + qq0) ? s00 * 0.125f : -1e30f;
        s01 = (k0 + kl1 <= MEM + q0 + qq0) ? s01 * 0.125f : -1e30f;
        s10 = (k0 + kl0 <= MEM + q0 + qq1) ? s10 * 0.125f : -1e30f;
        s11 = (k0 + kl1 <= MEM + q0 + qq1) ? s11 * 0.125f : -1e30f;

        // ---- online softmax (rows owned by 16 consecutive lanes) ----
        float t0 = fmaxf(s00, s01), t1 = fmaxf(s10, s11);
        #pragma unroll
        for (int msk = 1; msk < 16; msk <<= 1) {
            t0 = fmaxf(t0, __shfl_xor(t0, msk, 64));
            t1 = fmaxf(t1, __shfl_xor(t1, msk, 64));
        }
        const float mn0 = fmaxf(m0, t0), mn1 = fmaxf(m1, t1);
        const float p00 = __expf(s00 - mn0), p01 = __expf(s01 - mn0);
        const float p10 = __expf(s10 - mn1), p11 = __expf(s11 - mn1);
        float w0 = p00 + p01, w1 = p10 + p11;
        #pragma unroll
        for (int msk = 1; msk < 16; msk <<= 1) {
            w0 += __shfl_xor(w0, msk, 64);
            w1 += __shfl_xor(w1, msk, 64);
        }
        const float al0 = __expf(m0 - mn0), al1 = __expf(m1 - mn1);
        l0 = l0 * al0 + w0; l1 = l1 * al1 + w1;
        m0 = mn0; m1 = mn1;
        #pragma unroll
        for (int i = 0; i < 4; ++i) { o0[i] *= al0; o1[i] *= al1; }
        Ps[qq0][kl0] = p00; Ps[qq0][kl1] = p01;
        Ps[qq1][kl0] = p10; Ps[qq1][kl1] = p11;
        __syncthreads();

        // ---- PV: o[qq][kp*4..+3] += P[qq][kl] * V[kl][...] ----
        #pragma unroll
        for (int kl = 0; kl < KT; kl += 2) {
            const float2 pa = *(const float2*)&Ps[qq0][kl];
            const float2 pb = *(const float2*)&Ps[qq1][kl];
            const float4 v0 = *(const float4*)&Vs[kl][kp * 4];
            const float4 v1 = *(const float4*)&Vs[kl + 1][kp * 4];
            o0[0] = fmaf(pa.x, v0.x, fmaf(pa.y, v1.x, o0[0]));
            o0[1] = fmaf(pa.x, v0.y, fmaf(pa.y, v1.y, o0[1]));
            o0[2] = fmaf(pa.x, v0.z, fmaf(pa.y, v1.z, o0[2]));
            o0[3] = fmaf(pa.x, v0.w, fmaf(pa.y, v1.w, o0[3]));
            o1[0] = fmaf(pb.x, v0.x, fmaf(pb.y, v1.x, o1[0]));
            o1[1] = fmaf(pb.x, v0.y, fmaf(pb.y, v1.y, o1[1]));
            o1[2] = fmaf(pb.x, v0.z, fmaf(pb.y, v1.z, o1[2]));
            o1[3] = fmaf(pb.x, v0.w, fmaf(pb.y, v1.w, o1[3]));
        }
    }

    const float i0 = 1.0f / l0, i1 = 1.0f / l1;
    float* po0 = O + ((size_t)(b * S + q0 + qq0)) * E + h * DH + kp * 4;
    float* po1 = O + ((size_t)(b * S + q0 + qq1)) * E + h * DH + kp * 4;
    *(float4*)po0 = make_float4(o0[0] * i0, o0[1] * i0, o0[2] * i0, o0[3] * i0);
    *(float4*)po1 = make_float4(o1[0] * i1, o1[1] * i1, o1[2] * i1, o1[3] * i1);
}

extern "C" void kernel_launch(void* const* d_in, const int* in_sizes, int n_in,
                              void* d_out, int out_size, void* d_ws, size_t ws_size,
                              hipStream_t stream)
{
    const float* obs  = (const float*)d_in[0];
    const float* mem  = (const float*)d_in[1];
    // d_in[2] = mask: deterministic (k <= MEM + q), recomputed in-kernel
    const float* Wenc = (const float*)d_in[3];
    const float* benc = (const float*)d_in[4];
    const float* ln1s = (const float*)d_in[5];
    const float* ln1b = (const float*)d_in[6];
    const float* Wq   = (const float*)d_in[7];
    const float* bq   = (const float*)d_in[8];
    const float* Wk   = (const float*)d_in[9];
    const float* bk   = (const float*)d_in[10];
    const float* Wv   = (const float*)d_in[11];
    const float* bv   = (const float*)d_in[12];
    const float* Wr   = (const float*)d_in[13];
    const float* ub   = (const float*)d_in[14];
    const float* vb   = (const float*)d_in[15];
    const float* Wo   = (const float*)d_in[16];
    const float* bo   = (const float*)d_in[17];
    const float* ln2s = (const float*)d_in[18];
    const float* ln2b = (const float*)d_in[19];
    const float* W1   = (const float*)d_in[20];
    const float* b1   = (const float*)d_in[21];
    const float* W2   = (const float*)d_in[22];
    const float* b2   = (const float*)d_in[23];

    float* ws = (float*)d_ws;
    size_t off = 0;
    float* X  = ws + off; off += (size_t)B * S * E;      // 2M
    float* PE = ws + off; off += (size_t)KLEN * E;       // 0.5M
    float* VK = ws + off; off += (size_t)B * KLEN * E;   // 4M  (reused as FF1)
    float* KB = ws + off; off += (size_t)B * KLEN * E;   // 4M
    float* VB = ws + off; off += (size_t)B * KLEN * E;   // 4M
    float* QN = ws + off; off += (size_t)B * S * E;      // 2M  (qn / hn)
    float* QB = ws + off; off += (size_t)B * S * E;      // 2M
    float* RB = ws + off; off += (size_t)KLEN * E;       // 0.5M
    float* OB = ws + off; off += (size_t)B * S * E;      // 2M
    float* HB = ws + off; off += (size_t)B * S * E;      // 2M
    float* FF = VK;                                      // reuse (vk dead by then)

    pe_kernel<<<(KLEN * E) / 256, 256, 0, stream>>>(PE);
    gemm_kernel<<<dim3(E / 64, (B * S) / 64), 256, 0, stream>>>(
        obs, OBS, Wenc, benc, nullptr, X, B * S, E, OBS, 0);

    for (int li = 0; li < L; ++li) {
        const size_t wOff = (size_t)li * E * E;
        const size_t vOff = (size_t)li * E;   // E == H*DH

        ln_mem_kernel<<<B * MEM, 256, 0, stream>>>(mem, li, ln1s + vOff, ln1b + vOff, VK);
        ln_f32_kernel<<<B * S, 256, 0, stream>>>(X, ln1s + vOff, ln1b + vOff, QN, VK);

        gemm_kernel<<<dim3(E / 64, (B * S) / 64), 256, 0, stream>>>(
            QN, E, Wq + wOff, bq + vOff, nullptr, QB, B * S, E, E, 0);
        gemm_kernel<<<dim3(E / 64, (B * KLEN) / 64), 256, 0, stream>>>(
            VK, E, Wk + wOff, bk + vOff, nullptr, KB, B * KLEN, E, E, 0);
        gemm_kernel<<<dim3(E / 64, (B * KLEN) / 64), 256, 0, stream>>>(
            VK, E, Wv + wOff, bv + vOff, nullptr, VB, B * KLEN, E, E, 0);
        gemm_kernel<<<dim3(E / 64, KLEN / 64), 256, 0, stream>>>(
            PE, E, Wr + wOff, nullptr, nullptr, RB, KLEN, E, E, 0);

        flash_attn_kernel<<<dim3(S / QC, H, B), 256, 0, stream>>>(
            QB, KB, VB, RB, ub + vOff, vb + vOff, OB);

        gemm_kernel<<<dim3(E / 64, (B * S) / 64), 256, 0, stream>>>(
            OB, E, Wo + wOff, bo + vOff, X, HB, B * S, E, E, 0);
        ln_f32_kernel<<<B * S, 256, 0, stream>>>(HB, ln2s + vOff, ln2b + vOff, QN, nullptr);
        gemm_kernel<<<dim3(E / 64, (B * S) / 64), 256, 0, stream>>>(
            QN, E, W1 + wOff, b1 + vOff, nullptr, FF, B * S, E, E, 1);
        gemm_kernel<<<dim3(E / 64, (B * S) / 64), 256, 0, stream>>>(
            FF, E, W2 + wOff, b2 + vOff, HB, X, B * S, E, E, 0);
    }

    hipMemcpyAsync(d_out, X, (size_t)B * S * E * sizeof(float),
                   hipMemcpyDeviceToDevice, stream);
}

// Round 4
// 2329.101 us; speedup vs baseline: 3.6856x; 1.2103x over previous
//
#include <hip/hip_runtime.h>
#include <hip/hip_bf16.h>
#include <math.h>

#define B     8
#define S     512
#define MEM   512
#define L     4
#define E     512
#define H     8
#define DH    64
#define OBS   128
#define KLEN  1024   // MEM + S
#define QC    32     // q rows per attention block
#define KT    32     // k cols per attention tile

typedef __hip_bfloat16 bf16;
using frag_ab = __attribute__((ext_vector_type(8))) short;   // 8 bf16 (4 VGPRs)
using frag_cd = __attribute__((ext_vector_type(4))) float;   // 4 fp32 acc

__device__ __forceinline__ float gelu_tanh(float x) {
    return 0.5f * x * (1.0f + tanhf(0.7978845608028654f * (x + 0.044715f * x * x * x)));
}

// ---------------- positional embedding (bf16 out) ----------------------------
__global__ __launch_bounds__(256) void pe_kernel(bf16* __restrict__ pe) {
    const int idx = blockIdx.x * 256 + threadIdx.x;
    const int p = idx >> 9;        // row (E=512)
    const int j = idx & 511;
    const float pos = (float)(KLEN - p);       // pos_seq = [K, K-1, ..., 1]
    const int m = (j < 256) ? j : (j - 256);
    const float invf = expf(-(float)(2 * m) * (9.210340371976184f / (float)E));
    const float a = pos * invf;
    pe[idx] = __float2bfloat16((j < 256) ? sinf(a) : cosf(a));
}

// ---------------- obs fp32 -> bf16 cast --------------------------------------
__global__ __launch_bounds__(256) void cast_obs_kernel(const float* __restrict__ x,
                                                       bf16* __restrict__ o) {
    const int i = blockIdx.x * 256 + threadIdx.x;
    o[i] = __float2bfloat16(x[i]);
}

// ---------------- weight transpose+cast: W[Kd][Nd] fp32 -> Wt[Nd][Kd] bf16 ---
__global__ __launch_bounds__(256) void transpose_cast_kernel(
    const float* __restrict__ W, bf16* __restrict__ Wt, int Kd, int Nd)
{
    __shared__ float t[32][33];
    const int bn = blockIdx.x * 32, bk = blockIdx.y * 32, li = blockIdx.z;
    const float* Wp = W + (size_t)li * Kd * Nd;
    bf16* Wtp = Wt + (size_t)li * Kd * Nd;
    const int tx = threadIdx.x & 31, ty = threadIdx.x >> 5;   // 32 x 8
    #pragma unroll
    for (int r = 0; r < 32; r += 8)
        t[ty + r][tx] = Wp[(size_t)(bk + ty + r) * Nd + bn + tx];
    __syncthreads();
    #pragma unroll
    for (int r = 0; r < 32; r += 8)
        Wtp[(size_t)(bn + ty + r) * Kd + bk + tx] = __float2bfloat16(t[tx][ty + r]);
}

// ---------------- bf16 MFMA GEMM: C[M,N] = act(A@B + bias) + res -------------
// A: [M][K] bf16, Bt: [N][K] bf16 (B transposed). 128x128 tile, BK=32, 4 waves.
__global__ __launch_bounds__(256) void mfma_gemm_kernel(
    const bf16* __restrict__ A,
    const bf16* __restrict__ Bt,
    const float* __restrict__ bias,  // [N] fp32 or null
    const float* __restrict__ res,   // [M][N] fp32 or null
    float* __restrict__ Cf,          // fp32 out or null
    bf16* __restrict__ Cb,           // bf16 out or null
    int M, int N, int K, int act)
{
    __shared__ short As[128 * 32];
    __shared__ short Bs[128 * 32];
    const int tid = threadIdx.x;
    const int n0 = blockIdx.x * 128, m0 = blockIdx.y * 128;
    const int w = tid >> 6, lane = tid & 63;
    const int wm = (w >> 1) << 6, wn = (w & 1) << 6;
    const int fr = lane & 15, fq = lane >> 4;

    const int srow = tid >> 1, scol = (tid & 1) << 4;   // staging row / 16-col half
    const short* Ag = (const short*)A + (size_t)(m0 + srow) * K + scol;
    const short* Bg = (const short*)Bt + (size_t)(n0 + srow) * K + scol;
    short* Asw = &As[srow * 32 + scol];
    short* Bsw = &Bs[srow * 32 + scol];

    frag_cd acc[4][4];
    #pragma unroll
    for (int i = 0; i < 4; ++i)
        #pragma unroll
        for (int j = 0; j < 4; ++j)
            acc[i][j] = (frag_cd)(0.0f);

    for (int k0 = 0; k0 < K; k0 += 32) {
        const uint4 a0 = *(const uint4*)(Ag + k0);
        const uint4 a1 = *(const uint4*)(Ag + k0 + 8);
        const uint4 b0 = *(const uint4*)(Bg + k0);
        const uint4 b1 = *(const uint4*)(Bg + k0 + 8);
        __syncthreads();    // previous iteration's LDS reads complete
        *(uint4*)(Asw) = a0; *(uint4*)(Asw + 8) = a1;
        *(uint4*)(Bsw) = b0; *(uint4*)(Bsw + 8) = b1;
        __syncthreads();
        frag_ab af[4], bfr[4];
        #pragma unroll
        for (int i = 0; i < 4; ++i) {
            af[i]  = *(const frag_ab*)&As[(wm + i * 16 + fr) * 32 + fq * 8];
            bfr[i] = *(const frag_ab*)&Bs[(wn + i * 16 + fr) * 32 + fq * 8];
        }
        #pragma unroll
        for (int i = 0; i < 4; ++i)
            #pragma unroll
            for (int j = 0; j < 4; ++j)
                acc[i][j] = __builtin_amdgcn_mfma_f32_16x16x32_bf16(af[i], bfr[j], acc[i][j], 0, 0, 0);
    }

    #pragma unroll
    for (int i = 0; i < 4; ++i) {
        #pragma unroll
        for (int r = 0; r < 4; ++r) {
            const int m = m0 + wm + i * 16 + fq * 4 + r;
            #pragma unroll
            for (int j = 0; j < 4; ++j) {
                const int n = n0 + wn + j * 16 + fr;
                float v = acc[i][j][r];
                if (bias) v += bias[n];
                if (act)  v = gelu_tanh(v);
                if (res)  v += res[(size_t)m * N + n];
                if (Cf) Cf[(size_t)m * N + n] = v;
                if (Cb) Cb[(size_t)m * N + n] = __float2bfloat16(v);
            }
        }
    }
}

// ---------------- LayerNorm over E=512, one block per row --------------------
// memories source (fp32): row rr = b*MEM+kp -> vk_b[b*KLEN + kp] (bf16)
__global__ __launch_bounds__(256) void ln_mem_kernel(
    const float* __restrict__ mem, int li,
    const float* __restrict__ gam, const float* __restrict__ bet,
    bf16* __restrict__ vkdst)
{
    const int rr = blockIdx.x;
    const int t = threadIdx.x;
    const float* sp = mem + ((size_t)rr * L + li) * E;
    const float x0 = sp[t], x1 = sp[t + 256];
    float s = x0 + x1, ss = fmaf(x0, x0, x1 * x1);
    #pragma unroll
    for (int off = 32; off; off >>= 1) { s += __shfl_down(s, off, 64); ss += __shfl_down(ss, off, 64); }
    __shared__ float tmp[8];
    const int wid = t >> 6, lane = t & 63;
    if (!lane) { tmp[wid] = s; tmp[4 + wid] = ss; }
    __syncthreads();
    s = tmp[0] + tmp[1] + tmp[2] + tmp[3];
    ss = tmp[4] + tmp[5] + tmp[6] + tmp[7];
    const float mean = s * (1.0f / E);
    const float var = ss * (1.0f / E) - mean * mean;
    const float rstd = rsqrtf(var + 1e-6f);
    const int b = rr >> 9, kp = rr & 511;  // MEM = 512
    bf16* dst = vkdst + ((size_t)b * KLEN + kp) * E;
    dst[t]       = __float2bfloat16((x0 - mean) * rstd * gam[t] + bet[t]);
    dst[t + 256] = __float2bfloat16((x1 - mean) * rstd * gam[t + 256] + bet[t + 256]);
}

// fp32 source -> dst1 bf16 [rr*E]; optionally also vk_b[b*KLEN + MEM + s]
__global__ __launch_bounds__(256) void ln_f32_kernel(
    const float* __restrict__ src,
    const float* __restrict__ gam, const float* __restrict__ bet,
    bf16* __restrict__ dst1, bf16* __restrict__ vkdst)
{
    const int rr = blockIdx.x;
    const int t = threadIdx.x;
    const float* sp = src + (size_t)rr * E;
    const float x0 = sp[t], x1 = sp[t + 256];
    float s = x0 + x1, ss = fmaf(x0, x0, x1 * x1);
    #pragma unroll
    for (int off = 32; off; off >>= 1) { s += __shfl_down(s, off, 64); ss += __shfl_down(ss, off, 64); }
    __shared__ float tmp[8];
    const int wid = t >> 6, lane = t & 63;
    if (!lane) { tmp[wid] = s; tmp[4 + wid] = ss; }
    __syncthreads();
    s = tmp[0] + tmp[1] + tmp[2] + tmp[3];
    ss = tmp[4] + tmp[5] + tmp[6] + tmp[7];
    const float mean = s * (1.0f / E);
    const float var = ss * (1.0f / E) - mean * mean;
    const float rstd = rsqrtf(var + 1e-6f);
    const float y0 = (x0 - mean) * rstd * gam[t] + bet[t];
    const float y1 = (x1 - mean) * rstd * gam[t + 256] + bet[t + 256];
    dst1[(size_t)rr * E + t]       = __float2bfloat16(y0);
    dst1[(size_t)rr * E + t + 256] = __float2bfloat16(y1);
    if (vkdst) {
        const int b = rr >> 9, spos = rr & 511;   // S = 512
        bf16* d2 = vkdst + ((size_t)b * KLEN + MEM + spos) * E;
        d2[t] = __float2bfloat16(y0); d2[t + 256] = __float2bfloat16(y1);
    }
}

// ---------------- fused flash attention (fp32 compute, bf16 O out) -----------
__global__ __launch_bounds__(256) void flash_attn_kernel(
    const float* __restrict__ Q,   // [B*S, E]
    const float* __restrict__ Kb,  // [B*KLEN, E]
    const float* __restrict__ Vb,  // [B*KLEN, E]
    const float* __restrict__ Rb,  // [KLEN, E]
    const float* __restrict__ ub,  // [H*DH] layer slice
    const float* __restrict__ vbias,
    bf16* __restrict__ O)          // [B*S, E] bf16
{
    const int qc = blockIdx.x, h = blockIdx.y, b = blockIdx.z;
    const int q0 = qc * QC;
    const int t = threadIdx.x;
    const int qp = t >> 4, kp = t & 15;
    const int qq0 = 2 * qp, qq1 = qq0 + 1;
    const int kl0 = kp, kl1 = kp + 16;

    __shared__ __align__(16) float Qu[QC][68];
    __shared__ __align__(16) float Qv[QC][68];
    __shared__ __align__(16) float Ks[KT][68];
    __shared__ __align__(16) float Rs[KT + QC][68];
    __shared__ __align__(16) float Vs[KT][68];
    __shared__ __align__(16) float Ps[QC][36];

    {
        const int qq = t >> 3, dq = (t & 7) * 8;
        const float* qrow = Q + ((size_t)(b * S + q0 + qq)) * E + h * DH;
        const float4 a0 = *(const float4*)(qrow + dq);
        const float4 a1 = *(const float4*)(qrow + dq + 4);
        const float4 u0 = *(const float4*)(ub + h * DH + dq);
        const float4 u1 = *(const float4*)(ub + h * DH + dq + 4);
        const float4 v0 = *(const float4*)(vbias + h * DH + dq);
        const float4 v1 = *(const float4*)(vbias + h * DH + dq + 4);
        *(float4*)&Qu[qq][dq]   = make_float4(a0.x+u0.x, a0.y+u0.y, a0.z+u0.z, a0.w+u0.w);
        *(float4*)&Qu[qq][dq+4] = make_float4(a1.x+u1.x, a1.y+u1.y, a1.z+u1.z, a1.w+u1.w);
        *(float4*)&Qv[qq][dq]   = make_float4(a0.x+v0.x, a0.y+v0.y, a0.z+v0.z, a0.w+v0.w);
        *(float4*)&Qv[qq][dq+4] = make_float4(a1.x+v1.x, a1.y+v1.y, a1.z+v1.z, a1.w+v1.w);
    }

    float o0[4] = {0.f, 0.f, 0.f, 0.f};
    float o1[4] = {0.f, 0.f, 0.f, 0.f};
    float m0 = -3.0e38f, m1 = -3.0e38f, l0 = 0.f, l1 = 0.f;

    const int ntiles = ((MEM + q0 + QC - 1) >> 5) + 1;
    const int r00 = kp - 2 * qp + (QC - 1);

    for (int kt = 0; kt < ntiles; ++kt) {
        const int k0 = kt * KT;
        __syncthreads();
        {
            const int kk = t >> 3, dq = (t & 7) * 8;
            const float* kr = Kb + ((size_t)(b * KLEN + k0 + kk)) * E + h * DH;
            const float* vr = Vb + ((size_t)(b * KLEN + k0 + kk)) * E + h * DH;
            *(float4*)&Ks[kk][dq]     = *(const float4*)(kr + dq);
            *(float4*)&Ks[kk][dq + 4] = *(const float4*)(kr + dq + 4);
            *(float4*)&Vs[kk][dq]     = *(const float4*)(vr + dq);
            *(float4*)&Vs[kk][dq + 4] = *(const float4*)(vr + dq + 4);
        }
        {
            const int rbase = k0 + (S - 1) - q0 - (QC - 1);
            const int rr = t >> 2, dq = (t & 3) * 16;
            int j = rbase + rr; if (j > KLEN - 1) j = KLEN - 1;
            const float* rrow = Rb + (size_t)j * E + h * DH;
            *(float4*)&Rs[rr][dq]      = *(const float4*)(rrow + dq);
            *(float4*)&Rs[rr][dq + 4]  = *(const float4*)(rrow + dq + 4);
            *(float4*)&Rs[rr][dq + 8]  = *(const float4*)(rrow + dq + 8);
            *(float4*)&Rs[rr][dq + 12] = *(const float4*)(rrow + dq + 12);
        }
        __syncthreads();

        float s00 = 0.f, s01 = 0.f, s10 = 0.f, s11 = 0.f;
        #pragma unroll
        for (int d = 0; d < DH; d += 4) {
            const float4 a0 = *(const float4*)&Qu[qq0][d];
            const float4 a1 = *(const float4*)&Qu[qq1][d];
            const float4 c0 = *(const float4*)&Qv[qq0][d];
            const float4 c1 = *(const float4*)&Qv[qq1][d];
            const float4 k0v = *(const float4*)&Ks[kl0][d];
            const float4 k1v = *(const float4*)&Ks[kl1][d];
            const float4 rA = *(const float4*)&Rs[r00][d];
            const float4 rB = *(const float4*)&Rs[r00 - 1][d];
            const float4 rC = *(const float4*)&Rs[r00 + 16][d];
            const float4 rD = *(const float4*)&Rs[r00 + 15][d];
            s00 = fmaf(a0.x,k0v.x,fmaf(a0.y,k0v.y,fmaf(a0.z,k0v.z,fmaf(a0.w,k0v.w,s00))));
            s00 = fmaf(c0.x,rA.x, fmaf(c0.y,rA.y, fmaf(c0.z,rA.z, fmaf(c0.w,rA.w, s00))));
            s01 = fmaf(a0.x,k1v.x,fmaf(a0.y,k1v.y,fmaf(a0.z,k1v.z,fmaf(a0.w,k1v.w,s01))));
            s01 = fmaf(c0.x,rC.x, fmaf(c0.y,rC.y, fmaf(c0.z,rC.z, fmaf(c0.w,rC.w, s01))));
            s10 = fmaf(a1.x,k0v.x,fmaf(a1.y,k0v.y,fmaf(a1.z,k0v.z,fmaf(a1.w,k0v.w,s10))));
            s10 = fmaf(c1.x,rB.x, fmaf(c1.y,rB.y, fmaf(c1.z,rB.z, fmaf(c1.w,rB.w, s10))));
            s11 = fmaf(a1.x,k1v.x,fmaf(a1.y,k1v.y,fmaf(a1.z,k1v.z,fmaf(a1.w,k1v.w,s11))));
            s11 = fmaf(c1.x,rD.x, fmaf(c1.y,rD.y, fmaf(c1.z,rD.z, fmaf(c1.w,rD.w, s11))));
        }
        s00 = (k0 + kl0 <= MEM + q0 + qq0) ? s00 * 0.125f : -1e30f;
        s01 = (k0 + kl1 <= MEM + q0 + qq0) ? s01 * 0.125f : -1e30f;
        s10 = (k0 + kl0 <= MEM + q0 + qq1) ? s10 * 0.125f : -1e30f;
        s11 = (k0 + kl1 <= MEM + q0 + qq1) ? s11 * 0.125f : -1e30f;

        float t0 = fmaxf(s00, s01), t1 = fmaxf(s10, s11);
        #pragma unroll
        for (int msk = 1; msk < 16; msk <<= 1) {
            t0 = fmaxf(t0, __shfl_xor(t0, msk, 64));
            t1 = fmaxf(t1, __shfl_xor(t1, msk, 64));
        }
        const float mn0 = fmaxf(m0, t0), mn1 = fmaxf(m1, t1);
        const float p00 = __expf(s00 - mn0), p01 = __expf(s01 - mn0);
        const float p10 = __expf(s10 - mn1), p11 = __expf(s11 - mn1);
        float w0 = p00 + p01, w1 = p10 + p11;
        #pragma unroll
        for (int msk = 1; msk < 16; msk <<= 1) {
            w0 += __shfl_xor(w0, msk, 64);
            w1 += __shfl_xor(w1, msk, 64);
        }
        const float al0 = __expf(m0 - mn0), al1 = __expf(m1 - mn1);
        l0 = l0 * al0 + w0; l1 = l1 * al1 + w1;
        m0 = mn0; m1 = mn1;
        #pragma unroll
        for (int i = 0; i < 4; ++i) { o0[i] *= al0; o1[i] *= al1; }
        Ps[qq0][kl0] = p00; Ps[qq0][kl1] = p01;
        Ps[qq1][kl0] = p10; Ps[qq1][kl1] = p11;
        __syncthreads();

        #pragma unroll
        for (int kl = 0; kl < KT; kl += 2) {
            const float2 pa = *(const float2*)&Ps[qq0][kl];
            const float2 pb = *(const float2*)&Ps[qq1][kl];
            const float4 v0 = *(const float4*)&Vs[kl][kp * 4];
            const float4 v1 = *(const float4*)&Vs[kl + 1][kp * 4];
            o0[0] = fmaf(pa.x, v0.x, fmaf(pa.y, v1.x, o0[0]));
            o0[1] = fmaf(pa.x, v0.y, fmaf(pa.y, v1.y, o0[1]));
            o0[2] = fmaf(pa.x, v0.z, fmaf(pa.y, v1.z, o0[2]));
            o0[3] = fmaf(pa.x, v0.w, fmaf(pa.y, v1.w, o0[3]));
            o1[0] = fmaf(pb.x, v0.x, fmaf(pb.y, v1.x, o1[0]));
            o1[1] = fmaf(pb.x, v0.y, fmaf(pb.y, v1.y, o1[1]));
            o1[2] = fmaf(pb.x, v0.z, fmaf(pb.y, v1.z, o1[2]));
            o1[3] = fmaf(pb.x, v0.w, fmaf(pb.y, v1.w, o1[3]));
        }
    }

    const float i0 = 1.0f / l0, i1 = 1.0f / l1;
    bf16* po0 = O + ((size_t)(b * S + q0 + qq0)) * E + h * DH + kp * 4;
    bf16* po1 = O + ((size_t)(b * S + q0 + qq1)) * E + h * DH + kp * 4;
    #pragma unroll
    for (int i = 0; i < 4; ++i) {
        po0[i] = __float2bfloat16(o0[i] * i0);
        po1[i] = __float2bfloat16(o1[i] * i1);
    }
}

extern "C" void kernel_launch(void* const* d_in, const int* in_sizes, int n_in,
                              void* d_out, int out_size, void* d_ws, size_t ws_size,
                              hipStream_t stream)
{
    const float* obs  = (const float*)d_in[0];
    const float* mem  = (const float*)d_in[1];
    // d_in[2] = mask: deterministic (k <= MEM + q), recomputed in-kernel
    const float* Wenc = (const float*)d_in[3];
    const float* benc = (const float*)d_in[4];
    const float* ln1s = (const float*)d_in[5];
    const float* ln1b = (const float*)d_in[6];
    const float* Wq   = (const float*)d_in[7];
    const float* bq   = (const float*)d_in[8];
    const float* Wk   = (const float*)d_in[9];
    const float* bk   = (const float*)d_in[10];
    const float* Wv   = (const float*)d_in[11];
    const float* bv   = (const float*)d_in[12];
    const float* Wr   = (const float*)d_in[13];
    const float* ub   = (const float*)d_in[14];
    const float* vb   = (const float*)d_in[15];
    const float* Wo   = (const float*)d_in[16];
    const float* bo   = (const float*)d_in[17];
    const float* ln2s = (const float*)d_in[18];
    const float* ln2b = (const float*)d_in[19];
    const float* W1   = (const float*)d_in[20];
    const float* b1   = (const float*)d_in[21];
    const float* W2   = (const float*)d_in[22];
    const float* b2   = (const float*)d_in[23];

    // ---- workspace carve-up: fp32 region then bf16 region ----
    float* wsf = (float*)d_ws;
    size_t off = 0;
    float* X  = wsf + off; off += (size_t)B * S * E;      // 2M fl
    float* QB = wsf + off; off += (size_t)B * S * E;      // 2M
    float* KB = wsf + off; off += (size_t)B * KLEN * E;   // 4M
    float* VB = wsf + off; off += (size_t)B * KLEN * E;   // 4M
    float* RB = wsf + off; off += (size_t)KLEN * E;       // 0.5M
    float* HB = wsf + off; off += (size_t)B * S * E;      // 2M
    bf16* wsb = (bf16*)(wsf + off);
    size_t ob = 0;
    bf16* OBSb = wsb + ob; ob += (size_t)B * S * OBS;     // 0.5M el
    bf16* QNb  = wsb + ob; ob += (size_t)B * S * E;       // 2M el (ln1-qn / ln2-hn)
    bf16* VKb  = wsb + ob; ob += (size_t)B * KLEN * E;    // 4M el
    bf16* PEb  = wsb + ob; ob += (size_t)KLEN * E;        // 0.5M el
    bf16* WencT= wsb + ob; ob += (size_t)OBS * E;
    bf16* WqT  = wsb + ob; ob += (size_t)L * E * E;
    bf16* WkT  = wsb + ob; ob += (size_t)L * E * E;
    bf16* WvT  = wsb + ob; ob += (size_t)L * E * E;
    bf16* WrT  = wsb + ob; ob += (size_t)L * E * E;
    bf16* WoT  = wsb + ob; ob += (size_t)L * E * E;
    bf16* W1T  = wsb + ob; ob += (size_t)L * E * E;
    bf16* W2T  = wsb + ob; ob += (size_t)L * E * E;
    bf16* OBb  = wsb + ob; ob += (size_t)B * S * E;       // 2M el (flash out)
    bf16* FFb  = wsb + ob; ob += (size_t)B * S * E;       // 2M el (gelu out)

    // ---- weight transpose+cast (per call; weights are inputs) ----
    transpose_cast_kernel<<<dim3(E / 32, OBS / 32, 1), 256, 0, stream>>>(Wenc, WencT, OBS, E);
    transpose_cast_kernel<<<dim3(E / 32, E / 32, L), 256, 0, stream>>>(Wq, WqT, E, E);
    transpose_cast_kernel<<<dim3(E / 32, E / 32, L), 256, 0, stream>>>(Wk, WkT, E, E);
    transpose_cast_kernel<<<dim3(E / 32, E / 32, L), 256, 0, stream>>>(Wv, WvT, E, E);
    transpose_cast_kernel<<<dim3(E / 32, E / 32, L), 256, 0, stream>>>(Wr, WrT, E, E);
    transpose_cast_kernel<<<dim3(E / 32, E / 32, L), 256, 0, stream>>>(Wo, WoT, E, E);
    transpose_cast_kernel<<<dim3(E / 32, E / 32, L), 256, 0, stream>>>(W1, W1T, E, E);
    transpose_cast_kernel<<<dim3(E / 32, E / 32, L), 256, 0, stream>>>(W2, W2T, E, E);

    cast_obs_kernel<<<(B * S * OBS) / 256, 256, 0, stream>>>(obs, OBSb);
    pe_kernel<<<(KLEN * E) / 256, 256, 0, stream>>>(PEb);

    // encoder: X = obs @ W_enc + b_enc (fp32 out)
    mfma_gemm_kernel<<<dim3(E / 128, (B * S) / 128), 256, 0, stream>>>(
        OBSb, WencT, benc, nullptr, X, nullptr, B * S, E, OBS, 0);

    for (int li = 0; li < L; ++li) {
        const size_t wOff = (size_t)li * E * E;
        const size_t vOff = (size_t)li * E;   // E == H*DH

        ln_mem_kernel<<<B * MEM, 256, 0, stream>>>(mem, li, ln1s + vOff, ln1b + vOff, VKb);
        ln_f32_kernel<<<B * S, 256, 0, stream>>>(X, ln1s + vOff, ln1b + vOff, QNb, VKb);

        mfma_gemm_kernel<<<dim3(E / 128, (B * S) / 128), 256, 0, stream>>>(
            QNb, WqT + wOff, bq + vOff, nullptr, QB, nullptr, B * S, E, E, 0);
        mfma_gemm_kernel<<<dim3(E / 128, (B * KLEN) / 128), 256, 0, stream>>>(
            VKb, WkT + wOff, bk + vOff, nullptr, KB, nullptr, B * KLEN, E, E, 0);
        mfma_gemm_kernel<<<dim3(E / 128, (B * KLEN) / 128), 256, 0, stream>>>(
            VKb, WvT + wOff, bv + vOff, nullptr, VB, nullptr, B * KLEN, E, E, 0);
        mfma_gemm_kernel<<<dim3(E / 128, KLEN / 128), 256, 0, stream>>>(
            PEb, WrT + wOff, nullptr, nullptr, RB, nullptr, KLEN, E, E, 0);

        flash_attn_kernel<<<dim3(S / QC, H, B), 256, 0, stream>>>(
            QB, KB, VB, RB, ub + vOff, vb + vOff, OBb);

        // HB = X + (O @ Wo + bo)
        mfma_gemm_kernel<<<dim3(E / 128, (B * S) / 128), 256, 0, stream>>>(
            OBb, WoT + wOff, bo + vOff, X, HB, nullptr, B * S, E, E, 0);
        // hn = ln2(HB) -> QNb
        ln_f32_kernel<<<B * S, 256, 0, stream>>>(HB, ln2s + vOff, ln2b + vOff, QNb, nullptr);
        // FFb = gelu(hn @ W1 + b1) (bf16 out)
        mfma_gemm_kernel<<<dim3(E / 128, (B * S) / 128), 256, 0, stream>>>(
            QNb, W1T + wOff, b1 + vOff, nullptr, nullptr, FFb, B * S, E, E, 1);
        // X = FF @ W2 + b2 + HB (fp32 out)
        mfma_gemm_kernel<<<dim3(E / 128, (B * S) / 128), 256, 0, stream>>>(
            FFb, W2T + wOff, b2 + vOff, HB, X, nullptr, B * S, E, E, 0);
    }

    hipMemcpyAsync(d_out, X, (size_t)B * S * E * sizeof(float),
                   hipMemcpyDeviceToDevice, stream);
}

// Round 5
// 1438.750 us; speedup vs baseline: 5.9664x; 1.6188x over previous
//
#include <hip/hip_runtime.h>
#include <hip/hip_bf16.h>
#include <math.h>

#define B     8
#define S     512
#define MEM   512
#define L     4
#define E     512
#define H     8
#define DH    64
#define OBS   128
#define KLEN  1024   // MEM + S
#define FQ    64     // flash: q rows per block
#define FK    64     // flash: k per tile

typedef __hip_bfloat16 bf16;
using frag_ab = __attribute__((ext_vector_type(8))) short;   // 8 bf16 (4 VGPRs)
using frag_cd = __attribute__((ext_vector_type(4))) float;   // 4 fp32 acc

__device__ __forceinline__ float gelu_tanh(float x) {
    return 0.5f * x * (1.0f + tanhf(0.7978845608028654f * (x + 0.044715f * x * x * x)));
}
__device__ __forceinline__ short f2bs(float x) { bf16 h = __float2bfloat16(x); return *(short*)&h; }
__device__ __forceinline__ float bs2f(short s) {
    union { unsigned u; float f; } t; t.u = ((unsigned)(unsigned short)s) << 16; return t.f;
}

// ---------------- positional embedding (bf16 out) ----------------------------
__global__ __launch_bounds__(256) void pe_kernel(bf16* __restrict__ pe) {
    const int idx = blockIdx.x * 256 + threadIdx.x;
    const int p = idx >> 9;
    const int j = idx & 511;
    const float pos = (float)(KLEN - p);
    const int m = (j < 256) ? j : (j - 256);
    const float invf = expf(-(float)(2 * m) * (9.210340371976184f / (float)E));
    const float a = pos * invf;
    pe[idx] = __float2bfloat16((j < 256) ? sinf(a) : cosf(a));
}

__global__ __launch_bounds__(256) void cast_obs_kernel(const float* __restrict__ x,
                                                       bf16* __restrict__ o) {
    const int i = blockIdx.x * 256 + threadIdx.x;
    o[i] = __float2bfloat16(x[i]);
}

// ---------------- weight transpose+cast: W[Kd][Nd] fp32 -> Wt[Nd][Kd] bf16 ---
__global__ __launch_bounds__(256) void transpose_cast_kernel(
    const float* __restrict__ W, bf16* __restrict__ Wt, int Kd, int Nd)
{
    __shared__ float t[32][33];
    const int bn = blockIdx.x * 32, bk = blockIdx.y * 32, li = blockIdx.z;
    const float* Wp = W + (size_t)li * Kd * Nd;
    bf16* Wtp = Wt + (size_t)li * Kd * Nd;
    const int tx = threadIdx.x & 31, ty = threadIdx.x >> 5;
    #pragma unroll
    for (int r = 0; r < 32; r += 8)
        t[ty + r][tx] = Wp[(size_t)(bk + ty + r) * Nd + bn + tx];
    __syncthreads();
    #pragma unroll
    for (int r = 0; r < 32; r += 8)
        Wtp[(size_t)(bn + ty + r) * Kd + bk + tx] = __float2bfloat16(t[tx][ty + r]);
}

// ---------------- V transpose: Vn[B*KLEN][E] bf16 -> Vt[B][E][KLEN] bf16 -----
__global__ __launch_bounds__(256) void transpose_v_kernel(
    const bf16* __restrict__ Vn, bf16* __restrict__ Vt)
{
    __shared__ short ts[64][72];
    const int k0 = blockIdx.x * 64, d0 = blockIdx.y * 64, b = blockIdx.z;
    const int t = threadIdx.x;
    const int r = t >> 2, c = (t & 3) * 16;
    const short* src = (const short*)Vn + ((size_t)(b * KLEN + k0 + r)) * E + d0 + c;
    *(uint4*)&ts[r][c]     = *(const uint4*)(src);
    *(uint4*)&ts[r][c + 8] = *(const uint4*)(src + 8);
    __syncthreads();
    short vals[16];
    #pragma unroll
    for (int i = 0; i < 16; ++i) vals[i] = ts[c + i][r];
    short* dst = (short*)Vt + ((size_t)(b * E + d0 + r)) * KLEN + k0 + c;
    *(uint4*)(dst)     = *(const uint4*)&vals[0];
    *(uint4*)(dst + 8) = *(const uint4*)&vals[8];
}

// ---------------- bf16 MFMA GEMM -------------------------------------------
// A:[M][K] bf16, Bt:[N][K] bf16. If Cb2: Cb=bf16(v+bias_u[n]), Cb2=bf16(v+bias_v[n]).
__global__ __launch_bounds__(256) void mfma_gemm_kernel(
    const bf16* __restrict__ A,
    const bf16* __restrict__ Bt,
    const float* __restrict__ bias,
    const float* __restrict__ bias_u,
    const float* __restrict__ bias_v,
    const float* __restrict__ res,
    float* __restrict__ Cf,
    bf16* __restrict__ Cb,
    bf16* __restrict__ Cb2,
    int M, int N, int K, int act)
{
    __shared__ short As[128 * 32];
    __shared__ short Bs[128 * 32];
    const int tid = threadIdx.x;
    const int n0 = blockIdx.x * 128, m0 = blockIdx.y * 128;
    const int w = tid >> 6, lane = tid & 63;
    const int wm = (w >> 1) << 6, wn = (w & 1) << 6;
    const int fr = lane & 15, fq = lane >> 4;

    const int srow = tid >> 1, scol = (tid & 1) << 4;
    const short* Ag = (const short*)A + (size_t)(m0 + srow) * K + scol;
    const short* Bg = (const short*)Bt + (size_t)(n0 + srow) * K + scol;
    short* Asw = &As[srow * 32 + scol];
    short* Bsw = &Bs[srow * 32 + scol];

    frag_cd acc[4][4];
    #pragma unroll
    for (int i = 0; i < 4; ++i)
        #pragma unroll
        for (int j = 0; j < 4; ++j)
            acc[i][j] = (frag_cd)(0.0f);

    for (int k0 = 0; k0 < K; k0 += 32) {
        const uint4 a0 = *(const uint4*)(Ag + k0);
        const uint4 a1 = *(const uint4*)(Ag + k0 + 8);
        const uint4 b0 = *(const uint4*)(Bg + k0);
        const uint4 b1 = *(const uint4*)(Bg + k0 + 8);
        __syncthreads();
        *(uint4*)(Asw) = a0; *(uint4*)(Asw + 8) = a1;
        *(uint4*)(Bsw) = b0; *(uint4*)(Bsw + 8) = b1;
        __syncthreads();
        frag_ab af[4], bfr[4];
        #pragma unroll
        for (int i = 0; i < 4; ++i) {
            af[i]  = *(const frag_ab*)&As[(wm + i * 16 + fr) * 32 + fq * 8];
            bfr[i] = *(const frag_ab*)&Bs[(wn + i * 16 + fr) * 32 + fq * 8];
        }
        #pragma unroll
        for (int i = 0; i < 4; ++i)
            #pragma unroll
            for (int j = 0; j < 4; ++j)
                acc[i][j] = __builtin_amdgcn_mfma_f32_16x16x32_bf16(af[i], bfr[j], acc[i][j], 0, 0, 0);
    }

    #pragma unroll
    for (int i = 0; i < 4; ++i) {
        #pragma unroll
        for (int r = 0; r < 4; ++r) {
            const int m = m0 + wm + i * 16 + fq * 4 + r;
            #pragma unroll
            for (int j = 0; j < 4; ++j) {
                const int n = n0 + wn + j * 16 + fr;
                float v = acc[i][j][r];
                if (bias) v += bias[n];
                if (act)  v = gelu_tanh(v);
                if (res)  v += res[(size_t)m * N + n];
                if (Cb2) {
                    Cb[(size_t)m * N + n]  = __float2bfloat16(v + bias_u[n]);
                    Cb2[(size_t)m * N + n] = __float2bfloat16(v + bias_v[n]);
                } else {
                    if (Cf) Cf[(size_t)m * N + n] = v;
                    if (Cb) Cb[(size_t)m * N + n] = __float2bfloat16(v);
                }
            }
        }
    }
}

// ---------------- BD GEMM: BD[h][b*S+q][j] = Qv[b,q,h,:]·R[j,h,:] ------------
__global__ __launch_bounds__(256) void bd_gemm_kernel(
    const bf16* __restrict__ Qv,   // [B*S][E]
    const bf16* __restrict__ R,    // [KLEN][E]
    bf16* __restrict__ BD)         // [H][B*S][KLEN]
{
    __shared__ short As[128 * 32];
    __shared__ short Bs[128 * 32];
    const int tid = threadIdx.x;
    const int n0 = blockIdx.x * 128, m0 = blockIdx.y * 128, h = blockIdx.z;
    const int w = tid >> 6, lane = tid & 63;
    const int wm = (w >> 1) << 6, wn = (w & 1) << 6;
    const int fr = lane & 15, fq = lane >> 4;

    const int srow = tid >> 1, scol = (tid & 1) << 4;
    const short* Ag = (const short*)Qv + (size_t)(m0 + srow) * E + h * DH + scol;
    const short* Bg = (const short*)R + (size_t)(n0 + srow) * E + h * DH + scol;
    short* Asw = &As[srow * 32 + scol];
    short* Bsw = &Bs[srow * 32 + scol];

    frag_cd acc[4][4];
    #pragma unroll
    for (int i = 0; i < 4; ++i)
        #pragma unroll
        for (int j = 0; j < 4; ++j)
            acc[i][j] = (frag_cd)(0.0f);

    #pragma unroll
    for (int k0 = 0; k0 < DH; k0 += 32) {
        const uint4 a0 = *(const uint4*)(Ag + k0);
        const uint4 a1 = *(const uint4*)(Ag + k0 + 8);
        const uint4 b0 = *(const uint4*)(Bg + k0);
        const uint4 b1 = *(const uint4*)(Bg + k0 + 8);
        __syncthreads();
        *(uint4*)(Asw) = a0; *(uint4*)(Asw + 8) = a1;
        *(uint4*)(Bsw) = b0; *(uint4*)(Bsw + 8) = b1;
        __syncthreads();
        frag_ab af[4], bfr[4];
        #pragma unroll
        for (int i = 0; i < 4; ++i) {
            af[i]  = *(const frag_ab*)&As[(wm + i * 16 + fr) * 32 + fq * 8];
            bfr[i] = *(const frag_ab*)&Bs[(wn + i * 16 + fr) * 32 + fq * 8];
        }
        #pragma unroll
        for (int i = 0; i < 4; ++i)
            #pragma unroll
            for (int j = 0; j < 4; ++j)
                acc[i][j] = __builtin_amdgcn_mfma_f32_16x16x32_bf16(af[i], bfr[j], acc[i][j], 0, 0, 0);
    }

    #pragma unroll
    for (int i = 0; i < 4; ++i)
        #pragma unroll
        for (int r = 0; r < 4; ++r) {
            const int m = m0 + wm + i * 16 + fq * 4 + r;
            #pragma unroll
            for (int j = 0; j < 4; ++j) {
                const int n = n0 + wn + j * 16 + fr;
                BD[((size_t)h * (B * S) + m) * KLEN + n] = __float2bfloat16(acc[i][j][r]);
            }
        }
}

// ---------------- LayerNorm kernels (unchanged from R4) ----------------------
__global__ __launch_bounds__(256) void ln_mem_kernel(
    const float* __restrict__ mem, int li,
    const float* __restrict__ gam, const float* __restrict__ bet,
    bf16* __restrict__ vkdst)
{
    const int rr = blockIdx.x;
    const int t = threadIdx.x;
    const float* sp = mem + ((size_t)rr * L + li) * E;
    const float x0 = sp[t], x1 = sp[t + 256];
    float s = x0 + x1, ss = fmaf(x0, x0, x1 * x1);
    #pragma unroll
    for (int off = 32; off; off >>= 1) { s += __shfl_down(s, off, 64); ss += __shfl_down(ss, off, 64); }
    __shared__ float tmp[8];
    const int wid = t >> 6, lane = t & 63;
    if (!lane) { tmp[wid] = s; tmp[4 + wid] = ss; }
    __syncthreads();
    s = tmp[0] + tmp[1] + tmp[2] + tmp[3];
    ss = tmp[4] + tmp[5] + tmp[6] + tmp[7];
    const float mean = s * (1.0f / E);
    const float var = ss * (1.0f / E) - mean * mean;
    const float rstd = rsqrtf(var + 1e-6f);
    const int b = rr >> 9, kp = rr & 511;
    bf16* dst = vkdst + ((size_t)b * KLEN + kp) * E;
    dst[t]       = __float2bfloat16((x0 - mean) * rstd * gam[t] + bet[t]);
    dst[t + 256] = __float2bfloat16((x1 - mean) * rstd * gam[t + 256] + bet[t + 256]);
}

__global__ __launch_bounds__(256) void ln_f32_kernel(
    const float* __restrict__ src,
    const float* __restrict__ gam, const float* __restrict__ bet,
    bf16* __restrict__ dst1, bf16* __restrict__ vkdst)
{
    const int rr = blockIdx.x;
    const int t = threadIdx.x;
    const float* sp = src + (size_t)rr * E;
    const float x0 = sp[t], x1 = sp[t + 256];
    float s = x0 + x1, ss = fmaf(x0, x0, x1 * x1);
    #pragma unroll
    for (int off = 32; off; off >>= 1) { s += __shfl_down(s, off, 64); ss += __shfl_down(ss, off, 64); }
    __shared__ float tmp[8];
    const int wid = t >> 6, lane = t & 63;
    if (!lane) { tmp[wid] = s; tmp[4 + wid] = ss; }
    __syncthreads();
    s = tmp[0] + tmp[1] + tmp[2] + tmp[3];
    ss = tmp[4] + tmp[5] + tmp[6] + tmp[7];
    const float mean = s * (1.0f / E);
    const float var = ss * (1.0f / E) - mean * mean;
    const float rstd = rsqrtf(var + 1e-6f);
    const float y0 = (x0 - mean) * rstd * gam[t] + bet[t];
    const float y1 = (x1 - mean) * rstd * gam[t + 256] + bet[t + 256];
    dst1[(size_t)rr * E + t]       = __float2bfloat16(y0);
    dst1[(size_t)rr * E + t + 256] = __float2bfloat16(y1);
    if (vkdst) {
        const int b = rr >> 9, spos = rr & 511;
        bf16* d2 = vkdst + ((size_t)b * KLEN + MEM + spos) * E;
        d2[t] = __float2bfloat16(y0); d2[t + 256] = __float2bfloat16(y1);
    }
}

// ---------------- MFMA flash attention ---------------------------------------
// block=(qt,h,b): 64 q rows (4 waves x 16), k-tiles of 64, online softmax.
// score = (Qu·K^T + BD[h][q][k+511-q]) * 0.125, mask k <= 512+q.
__global__ __launch_bounds__(256) void mfma_flash_kernel(
    const bf16* __restrict__ Qu,   // [B*S][E]
    const bf16* __restrict__ Kb,   // [B*KLEN][E]
    const bf16* __restrict__ Vt,   // [B][E][KLEN]
    const bf16* __restrict__ BD,   // [H][B*S][KLEN]
    bf16* __restrict__ O)          // [B*S][E]
{
    const int qt = blockIdx.x, h = blockIdx.y, b = blockIdx.z;
    const int q0 = qt * FQ;
    const int t = threadIdx.x;
    const int w = t >> 6, lane = t & 63;
    const int fr = lane & 15, quad = lane >> 4;
    const int qbase = q0 + w * 16;

    __shared__ short Ks[FK][72];
    __shared__ short Vs[64][72];       // [d][k]
    __shared__ short Ps[4][16][72];    // per-wave P

    // Q A-frags straight from global (one-time)
    const short* qptr = (const short*)Qu + ((size_t)(b * S + qbase + fr)) * E + h * DH + quad * 8;
    const frag_ab au0 = *(const frag_ab*)(qptr);
    const frag_ab au1 = *(const frag_ab*)(qptr + 32);

    frag_cd accO[4];
    #pragma unroll
    for (int i = 0; i < 4; ++i) accO[i] = (frag_cd)(0.0f);
    float mrow[4] = {-3.0e38f, -3.0e38f, -3.0e38f, -3.0e38f};
    float lrow[4] = {0.f, 0.f, 0.f, 0.f};

    const int srow = t >> 2, scol = (t & 3) * 16;
    const short* kg = (const short*)Kb + ((size_t)(b * KLEN + srow)) * E + h * DH + scol;
    const short* vg = (const short*)Vt + ((size_t)(b * E + h * DH + srow)) * KLEN + scol;
    const bf16* bdb = BD + ((size_t)h * (B * S) + b * S) * KLEN;

    const int ntiles = 9 + qt;
    for (int kt = 0; kt < ntiles; ++kt) {
        const int k0 = kt * FK;
        __syncthreads();
        {   // stage K[64k][64d] and V^T[64d][64k]
            const short* kp = kg + (size_t)k0 * E;
            *(uint4*)&Ks[srow][scol]     = *(const uint4*)(kp);
            *(uint4*)&Ks[srow][scol + 8] = *(const uint4*)(kp + 8);
            const short* vp = vg + k0;
            *(uint4*)&Vs[srow][scol]     = *(const uint4*)(vp);
            *(uint4*)&Vs[srow][scol + 8] = *(const uint4*)(vp + 8);
        }
        __syncthreads();

        // ---- S = Qu·K^T (4 n-tiles of 16 k) ----
        frag_cd sc[4];
        #pragma unroll
        for (int nt = 0; nt < 4; ++nt) {
            const frag_ab kf0 = *(const frag_ab*)&Ks[nt * 16 + fr][quad * 8];
            const frag_ab kf1 = *(const frag_ab*)&Ks[nt * 16 + fr][32 + quad * 8];
            frag_cd z = (frag_cd)(0.0f);
            z = __builtin_amdgcn_mfma_f32_16x16x32_bf16(au0, kf0, z, 0, 0, 0);
            z = __builtin_amdgcn_mfma_f32_16x16x32_bf16(au1, kf1, z, 0, 0, 0);
            sc[nt] = z;
        }

        // ---- +BD, mask, online softmax per C-row ----
        #pragma unroll
        for (int r = 0; r < 4; ++r) {
            const int qrow = qbase + quad * 4 + r;
            const bf16* bdq = bdb + (size_t)qrow * KLEN;
            float sv[4];
            #pragma unroll
            for (int nt = 0; nt < 4; ++nt) {
                const int kcol = k0 + nt * 16 + fr;
                int j = kcol + 511 - qrow; if (j > KLEN - 1) j = KLEN - 1;
                const float bd = __bfloat162float(bdq[j]);
                const float sval = (sc[nt][r] + bd) * 0.125f;
                sv[nt] = (kcol <= MEM + qrow) ? sval : -1e30f;
            }
            float tm = fmaxf(fmaxf(sv[0], sv[1]), fmaxf(sv[2], sv[3]));
            tm = fmaxf(tm, __shfl_xor(tm, 1, 64));
            tm = fmaxf(tm, __shfl_xor(tm, 2, 64));
            tm = fmaxf(tm, __shfl_xor(tm, 4, 64));
            tm = fmaxf(tm, __shfl_xor(tm, 8, 64));
            const float mn = fmaxf(mrow[r], tm);
            const float p0 = __expf(sv[0] - mn), p1 = __expf(sv[1] - mn);
            const float p2 = __expf(sv[2] - mn), p3 = __expf(sv[3] - mn);
            float ws = p0 + p1 + p2 + p3;
            ws += __shfl_xor(ws, 1, 64);
            ws += __shfl_xor(ws, 2, 64);
            ws += __shfl_xor(ws, 4, 64);
            ws += __shfl_xor(ws, 8, 64);
            const float al = __expf(mrow[r] - mn);
            lrow[r] = lrow[r] * al + ws;
            mrow[r] = mn;
            #pragma unroll
            for (int nt = 0; nt < 4; ++nt) accO[nt][r] *= al;
            const int prow = quad * 4 + r;
            Ps[w][prow][fr]      = f2bs(p0);
            Ps[w][prow][16 + fr] = f2bs(p1);
            Ps[w][prow][32 + fr] = f2bs(p2);
            Ps[w][prow][48 + fr] = f2bs(p3);
        }

        // ---- O += P·V (per-wave P; same-wave LDS, no barrier needed) ----
        const frag_ab pf0 = *(const frag_ab*)&Ps[w][fr][quad * 8];
        const frag_ab pf1 = *(const frag_ab*)&Ps[w][fr][32 + quad * 8];
        #pragma unroll
        for (int nt = 0; nt < 4; ++nt) {
            const frag_ab vf0 = *(const frag_ab*)&Vs[nt * 16 + fr][quad * 8];
            const frag_ab vf1 = *(const frag_ab*)&Vs[nt * 16 + fr][32 + quad * 8];
            accO[nt] = __builtin_amdgcn_mfma_f32_16x16x32_bf16(pf0, vf0, accO[nt], 0, 0, 0);
            accO[nt] = __builtin_amdgcn_mfma_f32_16x16x32_bf16(pf1, vf1, accO[nt], 0, 0, 0);
        }
    }

    #pragma unroll
    for (int r = 0; r < 4; ++r) {
        const float inv = 1.0f / lrow[r];
        bf16* po = O + ((size_t)(b * S + qbase + quad * 4 + r)) * E + h * DH + fr;
        #pragma unroll
        for (int nt = 0; nt < 4; ++nt)
            po[nt * 16] = __float2bfloat16(accO[nt][r] * inv);
    }
}

extern "C" void kernel_launch(void* const* d_in, const int* in_sizes, int n_in,
                              void* d_out, int out_size, void* d_ws, size_t ws_size,
                              hipStream_t stream)
{
    const float* obs  = (const float*)d_in[0];
    const float* mem  = (const float*)d_in[1];
    // d_in[2] = mask: deterministic (k <= MEM + q), recomputed in-kernel
    const float* Wenc = (const float*)d_in[3];
    const float* benc = (const float*)d_in[4];
    const float* ln1s = (const float*)d_in[5];
    const float* ln1b = (const float*)d_in[6];
    const float* Wq   = (const float*)d_in[7];
    const float* bq   = (const float*)d_in[8];
    const float* Wk   = (const float*)d_in[9];
    const float* bk   = (const float*)d_in[10];
    const float* Wv   = (const float*)d_in[11];
    const float* bv   = (const float*)d_in[12];
    const float* Wr   = (const float*)d_in[13];
    const float* ub   = (const float*)d_in[14];
    const float* vb   = (const float*)d_in[15];
    const float* Wo   = (const float*)d_in[16];
    const float* bo   = (const float*)d_in[17];
    const float* ln2s = (const float*)d_in[18];
    const float* ln2b = (const float*)d_in[19];
    const float* W1   = (const float*)d_in[20];
    const float* b1   = (const float*)d_in[21];
    const float* W2   = (const float*)d_in[22];
    const float* b2   = (const float*)d_in[23];

    // ---- workspace ----
    float* wsf = (float*)d_ws;
    float* X = wsf;                                   // fp32 [B*S*E], live whole pass
    bf16* wsb = (bf16*)(wsf + (size_t)B * S * E);
    size_t ob = 0;
    bf16* OBSb = wsb + ob; ob += (size_t)B * S * OBS;
    bf16* QNb  = wsb + ob; ob += (size_t)B * S * E;
    bf16* PEb  = wsb + ob; ob += (size_t)KLEN * E;
    bf16* RBb  = wsb + ob; ob += (size_t)KLEN * E;
    bf16* WencT= wsb + ob; ob += (size_t)OBS * E;
    bf16* WqT  = wsb + ob; ob += (size_t)L * E * E;
    bf16* WkT  = wsb + ob; ob += (size_t)L * E * E;
    bf16* WvT  = wsb + ob; ob += (size_t)L * E * E;
    bf16* WrT  = wsb + ob; ob += (size_t)L * E * E;
    bf16* WoT  = wsb + ob; ob += (size_t)L * E * E;
    bf16* W1T  = wsb + ob; ob += (size_t)L * E * E;
    bf16* W2T  = wsb + ob; ob += (size_t)L * E * E;
    bf16* QUb  = wsb + ob; ob += (size_t)B * S * E;
    bf16* QVb  = wsb + ob; ob += (size_t)B * S * E;
    bf16* KBb  = wsb + ob; ob += (size_t)B * KLEN * E;
    bf16* VTb  = wsb + ob; ob += (size_t)B * E * KLEN;
    bf16* OBb  = wsb + ob; ob += (size_t)B * S * E;
    // 64 MB union: BD ∪ {VKb, VBb} ∪ {HB, FFb} (disjoint lifetimes per layer)
    char* uni = (char*)(wsb + ob);
    bf16*  BDb = (bf16*)uni;                          // [H][B*S][KLEN] (64 MB)
    bf16*  VKb = (bf16*)uni;                          // [B*KLEN][E] (8 MB) @0
    bf16*  VBb = (bf16*)(uni + ((size_t)8 << 20));    // [B*KLEN][E] (8 MB) @8M
    float* HB  = (float*)uni;                         // [B*S][E] fp32 (8 MB) @0
    bf16*  FFb = (bf16*)(uni + ((size_t)8 << 20));    // [B*S][E] (4 MB) @8M

    // ---- weight transpose+cast ----
    transpose_cast_kernel<<<dim3(E / 32, OBS / 32, 1), 256, 0, stream>>>(Wenc, WencT, OBS, E);
    transpose_cast_kernel<<<dim3(E / 32, E / 32, L), 256, 0, stream>>>(Wq, WqT, E, E);
    transpose_cast_kernel<<<dim3(E / 32, E / 32, L), 256, 0, stream>>>(Wk, WkT, E, E);
    transpose_cast_kernel<<<dim3(E / 32, E / 32, L), 256, 0, stream>>>(Wv, WvT, E, E);
    transpose_cast_kernel<<<dim3(E / 32, E / 32, L), 256, 0, stream>>>(Wr, WrT, E, E);
    transpose_cast_kernel<<<dim3(E / 32, E / 32, L), 256, 0, stream>>>(Wo, WoT, E, E);
    transpose_cast_kernel<<<dim3(E / 32, E / 32, L), 256, 0, stream>>>(W1, W1T, E, E);
    transpose_cast_kernel<<<dim3(E / 32, E / 32, L), 256, 0, stream>>>(W2, W2T, E, E);

    cast_obs_kernel<<<(B * S * OBS) / 256, 256, 0, stream>>>(obs, OBSb);
    pe_kernel<<<(KLEN * E) / 256, 256, 0, stream>>>(PEb);

    // encoder: X = obs @ W_enc + b_enc (fp32)
    mfma_gemm_kernel<<<dim3(E / 128, (B * S) / 128), 256, 0, stream>>>(
        OBSb, WencT, benc, nullptr, nullptr, nullptr, X, nullptr, nullptr, B * S, E, OBS, 0);

    for (int li = 0; li < L; ++li) {
        const size_t wOff = (size_t)li * E * E;
        const size_t vOff = (size_t)li * E;

        ln_mem_kernel<<<B * MEM, 256, 0, stream>>>(mem, li, ln1s + vOff, ln1b + vOff, VKb);
        ln_f32_kernel<<<B * S, 256, 0, stream>>>(X, ln1s + vOff, ln1b + vOff, QNb, VKb);

        // Q -> QU/QV (bf16, dual bias)
        mfma_gemm_kernel<<<dim3(E / 128, (B * S) / 128), 256, 0, stream>>>(
            QNb, WqT + wOff, bq + vOff, ub + vOff, vb + vOff, nullptr,
            nullptr, QUb, QVb, B * S, E, E, 0);
        mfma_gemm_kernel<<<dim3(E / 128, (B * KLEN) / 128), 256, 0, stream>>>(
            VKb, WkT + wOff, bk + vOff, nullptr, nullptr, nullptr,
            nullptr, KBb, nullptr, B * KLEN, E, E, 0);
        mfma_gemm_kernel<<<dim3(E / 128, (B * KLEN) / 128), 256, 0, stream>>>(
            VKb, WvT + wOff, bv + vOff, nullptr, nullptr, nullptr,
            nullptr, VBb, nullptr, B * KLEN, E, E, 0);
        mfma_gemm_kernel<<<dim3(E / 128, KLEN / 128), 256, 0, stream>>>(
            PEb, WrT + wOff, nullptr, nullptr, nullptr, nullptr,
            nullptr, RBb, nullptr, KLEN, E, E, 0);

        transpose_v_kernel<<<dim3(KLEN / 64, E / 64, B), 256, 0, stream>>>(VBb, VTb);
        bd_gemm_kernel<<<dim3(KLEN / 128, (B * S) / 128, H), 256, 0, stream>>>(QVb, RBb, BDb);

        mfma_flash_kernel<<<dim3(S / FQ, H, B), 256, 0, stream>>>(QUb, KBb, VTb, BDb, OBb);

        // HB = X + (O @ Wo + bo)
        mfma_gemm_kernel<<<dim3(E / 128, (B * S) / 128), 256, 0, stream>>>(
            OBb, WoT + wOff, bo + vOff, nullptr, nullptr, X, HB, nullptr, nullptr, B * S, E, E, 0);
        ln_f32_kernel<<<B * S, 256, 0, stream>>>(HB, ln2s + vOff, ln2b + vOff, QNb, nullptr);
        // FFb = gelu(hn @ W1 + b1)
        mfma_gemm_kernel<<<dim3(E / 128, (B * S) / 128), 256, 0, stream>>>(
            QNb, W1T + wOff, b1 + vOff, nullptr, nullptr, nullptr,
            nullptr, FFb, nullptr, B * S, E, E, 1);
        // X = FF @ W2 + b2 + HB
        mfma_gemm_kernel<<<dim3(E / 128, (B * S) / 128), 256, 0, stream>>>(
            FFb, W2T + wOff, b2 + vOff, nullptr, nullptr, HB, X, nullptr, nullptr, B * S, E, E, 0);
    }

    hipMemcpyAsync(d_out, X, (size_t)B * S * E * sizeof(float),
                   hipMemcpyDeviceToDevice, stream);
}

// Round 6
// 1328.230 us; speedup vs baseline: 6.4628x; 1.0832x over previous
//
#include <hip/hip_runtime.h>
#include <hip/hip_bf16.h>
#include <math.h>

#define B     8
#define S     512
#define MEM   512
#define L     4
#define E     512
#define H     8
#define DH    64
#define OBS   128
#define KLEN  1024   // MEM + S
#define FQ    64     // flash: q rows per block
#define FK    64     // flash: k per tile

typedef __hip_bfloat16 bf16;
using frag_ab = __attribute__((ext_vector_type(8))) short;   // 8 bf16 (4 VGPRs)
using frag_cd = __attribute__((ext_vector_type(4))) float;   // 4 fp32 acc

__device__ __forceinline__ float gelu_tanh(float x) {
    return 0.5f * x * (1.0f + tanhf(0.7978845608028654f * (x + 0.044715f * x * x * x)));
}
__device__ __forceinline__ short f2bs(float x) { bf16 h = __float2bfloat16(x); return *(short*)&h; }
__device__ __forceinline__ float bs2f(short s) {
    union { unsigned u; float f; } t; t.u = ((unsigned)(unsigned short)s) << 16; return t.f;
}

// ---------------- positional embedding (bf16 out) ----------------------------
__global__ __launch_bounds__(256) void pe_kernel(bf16* __restrict__ pe) {
    const int idx = blockIdx.x * 256 + threadIdx.x;
    const int p = idx >> 9;
    const int j = idx & 511;
    const float pos = (float)(KLEN - p);
    const int m = (j < 256) ? j : (j - 256);
    const float invf = expf(-(float)(2 * m) * (9.210340371976184f / (float)E));
    const float a = pos * invf;
    pe[idx] = __float2bfloat16((j < 256) ? sinf(a) : cosf(a));
}

__global__ __launch_bounds__(256) void cast_obs_kernel(const float* __restrict__ x,
                                                       bf16* __restrict__ o) {
    const int i = blockIdx.x * 256 + threadIdx.x;
    o[i] = __float2bfloat16(x[i]);
}

// ------- weight transpose+cast: W[Kd][Nd] fp32 -> Wt[Nd][Kd] bf16 ------------
// layerStride: dst elements per layer (lets Wk/Wv interleave into WkvT).
__global__ __launch_bounds__(256) void transpose_cast_kernel(
    const float* __restrict__ W, bf16* __restrict__ Wt, int Kd, int Nd, int layerStride)
{
    __shared__ float t[32][33];
    const int bn = blockIdx.x * 32, bk = blockIdx.y * 32, li = blockIdx.z;
    const float* Wp = W + (size_t)li * Kd * Nd;
    bf16* Wtp = Wt + (size_t)li * layerStride;
    const int tx = threadIdx.x & 31, ty = threadIdx.x >> 5;
    #pragma unroll
    for (int r = 0; r < 32; r += 8)
        t[ty + r][tx] = Wp[(size_t)(bk + ty + r) * Nd + bn + tx];
    __syncthreads();
    #pragma unroll
    for (int r = 0; r < 32; r += 8)
        Wtp[(size_t)(bn + ty + r) * Kd + bk + tx] = __float2bfloat16(t[tx][ty + r]);
}

// ---------------- V transpose: Vn[B*KLEN][E] bf16 -> Vt[B][E][KLEN] bf16 -----
__global__ __launch_bounds__(256) void transpose_v_kernel(
    const bf16* __restrict__ Vn, bf16* __restrict__ Vt)
{
    __shared__ short ts[64][72];
    const int k0 = blockIdx.x * 64, d0 = blockIdx.y * 64, b = blockIdx.z;
    const int t = threadIdx.x;
    const int r = t >> 2, c = (t & 3) * 16;
    const short* src = (const short*)Vn + ((size_t)(b * KLEN + k0 + r)) * E + d0 + c;
    *(uint4*)&ts[r][c]     = *(const uint4*)(src);
    *(uint4*)&ts[r][c + 8] = *(const uint4*)(src + 8);
    __syncthreads();
    short vals[16];
    #pragma unroll
    for (int i = 0; i < 16; ++i) vals[i] = ts[c + i][r];
    short* dst = (short*)Vt + ((size_t)(b * E + d0 + r)) * KLEN + k0 + c;
    *(uint4*)(dst)     = *(const uint4*)&vals[0];
    *(uint4*)(dst + 8) = *(const uint4*)&vals[8];
}

// ---------------- bf16 MFMA GEMM ---------------------------------------------
// A:[M][K] bf16, Bt:[N][K] bf16.
// mode 0: v+=bias; act; +res; -> Cf (fp32) and/or Cb (bf16), stride N
// mode 1: v+=bias; Cb=bf16(v+bias_u[n]); Cb2=bf16(v+bias_v[n])         (Q dual)
// mode 2: N=1024 split: n<512 -> Cb[m*512+n]=bf16(v+bias_u[n])
//                       else  -> Cb2[m*512+n-512]=bf16(v+bias_v[n-512]) (K|V)
__global__ __launch_bounds__(256) void mfma_gemm_kernel(
    const bf16* __restrict__ A,
    const bf16* __restrict__ Bt,
    const float* __restrict__ bias,
    const float* __restrict__ bias_u,
    const float* __restrict__ bias_v,
    const float* __restrict__ res,
    float* __restrict__ Cf,
    bf16* __restrict__ Cb,
    bf16* __restrict__ Cb2,
    int M, int N, int K, int act, int mode)
{
    __shared__ short As[128 * 32];
    __shared__ short Bs[128 * 32];
    const int tid = threadIdx.x;
    const int n0 = blockIdx.x * 128, m0 = blockIdx.y * 128;
    const int w = tid >> 6, lane = tid & 63;
    const int wm = (w >> 1) << 6, wn = (w & 1) << 6;
    const int fr = lane & 15, fq = lane >> 4;

    const int srow = tid >> 1, scol = (tid & 1) << 4;
    const short* Ag = (const short*)A + (size_t)(m0 + srow) * K + scol;
    const short* Bg = (const short*)Bt + (size_t)(n0 + srow) * K + scol;
    short* Asw = &As[srow * 32 + scol];
    short* Bsw = &Bs[srow * 32 + scol];

    frag_cd acc[4][4];
    #pragma unroll
    for (int i = 0; i < 4; ++i)
        #pragma unroll
        for (int j = 0; j < 4; ++j)
            acc[i][j] = (frag_cd)(0.0f);

    for (int k0 = 0; k0 < K; k0 += 32) {
        const uint4 a0 = *(const uint4*)(Ag + k0);
        const uint4 a1 = *(const uint4*)(Ag + k0 + 8);
        const uint4 b0 = *(const uint4*)(Bg + k0);
        const uint4 b1 = *(const uint4*)(Bg + k0 + 8);
        __syncthreads();
        *(uint4*)(Asw) = a0; *(uint4*)(Asw + 8) = a1;
        *(uint4*)(Bsw) = b0; *(uint4*)(Bsw + 8) = b1;
        __syncthreads();
        frag_ab af[4], bfr[4];
        #pragma unroll
        for (int i = 0; i < 4; ++i) {
            af[i]  = *(const frag_ab*)&As[(wm + i * 16 + fr) * 32 + fq * 8];
            bfr[i] = *(const frag_ab*)&Bs[(wn + i * 16 + fr) * 32 + fq * 8];
        }
        #pragma unroll
        for (int i = 0; i < 4; ++i)
            #pragma unroll
            for (int j = 0; j < 4; ++j)
                acc[i][j] = __builtin_amdgcn_mfma_f32_16x16x32_bf16(af[i], bfr[j], acc[i][j], 0, 0, 0);
    }

    #pragma unroll
    for (int i = 0; i < 4; ++i) {
        #pragma unroll
        for (int r = 0; r < 4; ++r) {
            const int m = m0 + wm + i * 16 + fq * 4 + r;
            #pragma unroll
            for (int j = 0; j < 4; ++j) {
                const int n = n0 + wn + j * 16 + fr;
                float v = acc[i][j][r];
                if (bias) v += bias[n];
                if (act)  v = gelu_tanh(v);
                if (res)  v += res[(size_t)m * N + n];
                if (mode == 2) {
                    if (n < 512) Cb[(size_t)m * 512 + n] = __float2bfloat16(v + bias_u[n]);
                    else Cb2[(size_t)m * 512 + (n - 512)] = __float2bfloat16(v + bias_v[n - 512]);
                } else if (mode == 1) {
                    Cb[(size_t)m * N + n]  = __float2bfloat16(v + bias_u[n]);
                    Cb2[(size_t)m * N + n] = __float2bfloat16(v + bias_v[n]);
                } else {
                    if (Cf) Cf[(size_t)m * N + n] = v;
                    if (Cb) Cb[(size_t)m * N + n] = __float2bfloat16(v);
                }
            }
        }
    }
}

// ---------------- LayerNorm kernels ------------------------------------------
__global__ __launch_bounds__(256) void ln_mem_kernel(
    const float* __restrict__ mem, int li,
    const float* __restrict__ gam, const float* __restrict__ bet,
    bf16* __restrict__ vkdst)
{
    const int rr = blockIdx.x;
    const int t = threadIdx.x;
    const float* sp = mem + ((size_t)rr * L + li) * E;
    const float x0 = sp[t], x1 = sp[t + 256];
    float s = x0 + x1, ss = fmaf(x0, x0, x1 * x1);
    #pragma unroll
    for (int off = 32; off; off >>= 1) { s += __shfl_down(s, off, 64); ss += __shfl_down(ss, off, 64); }
    __shared__ float tmp[8];
    const int wid = t >> 6, lane = t & 63;
    if (!lane) { tmp[wid] = s; tmp[4 + wid] = ss; }
    __syncthreads();
    s = tmp[0] + tmp[1] + tmp[2] + tmp[3];
    ss = tmp[4] + tmp[5] + tmp[6] + tmp[7];
    const float mean = s * (1.0f / E);
    const float var = ss * (1.0f / E) - mean * mean;
    const float rstd = rsqrtf(var + 1e-6f);
    const int b = rr >> 9, kp = rr & 511;
    bf16* dst = vkdst + ((size_t)b * KLEN + kp) * E;
    dst[t]       = __float2bfloat16((x0 - mean) * rstd * gam[t] + bet[t]);
    dst[t + 256] = __float2bfloat16((x1 - mean) * rstd * gam[t + 256] + bet[t + 256]);
}

__global__ __launch_bounds__(256) void ln_f32_kernel(
    const float* __restrict__ src,
    const float* __restrict__ gam, const float* __restrict__ bet,
    bf16* __restrict__ dst1, bf16* __restrict__ vkdst)
{
    const int rr = blockIdx.x;
    const int t = threadIdx.x;
    const float* sp = src + (size_t)rr * E;
    const float x0 = sp[t], x1 = sp[t + 256];
    float s = x0 + x1, ss = fmaf(x0, x0, x1 * x1);
    #pragma unroll
    for (int off = 32; off; off >>= 1) { s += __shfl_down(s, off, 64); ss += __shfl_down(ss, off, 64); }
    __shared__ float tmp[8];
    const int wid = t >> 6, lane = t & 63;
    if (!lane) { tmp[wid] = s; tmp[4 + wid] = ss; }
    __syncthreads();
    s = tmp[0] + tmp[1] + tmp[2] + tmp[3];
    ss = tmp[4] + tmp[5] + tmp[6] + tmp[7];
    const float mean = s * (1.0f / E);
    const float var = ss * (1.0f / E) - mean * mean;
    const float rstd = rsqrtf(var + 1e-6f);
    const float y0 = (x0 - mean) * rstd * gam[t] + bet[t];
    const float y1 = (x1 - mean) * rstd * gam[t + 256] + bet[t + 256];
    dst1[(size_t)rr * E + t]       = __float2bfloat16(y0);
    dst1[(size_t)rr * E + t + 256] = __float2bfloat16(y1);
    if (vkdst) {
        const int b = rr >> 9, spos = rr & 511;
        bf16* d2 = vkdst + ((size_t)b * KLEN + MEM + spos) * E;
        d2[t] = __float2bfloat16(y0); d2[t + 256] = __float2bfloat16(y1);
    }
}

// ---------------- MFMA flash attention with in-LDS BD ------------------------
// block=(qt,h,b): 64 q rows (4 waves x 16), k-tiles of 64.
// score = (Qu·K^T + Qv·R[k+511-q]) * 0.125, mask k <= 512+q.
// R band (127 rows) staged in LDS; per-wave BD tile computed via MFMA into
// BDs, then read shifted. No BD HBM traffic.
__global__ __launch_bounds__(256) void mfma_flash_kernel(
    const bf16* __restrict__ Qu,   // [B*S][E]
    const bf16* __restrict__ Qv,   // [B*S][E]
    const bf16* __restrict__ Kb,   // [B*KLEN][E]
    const bf16* __restrict__ Vt,   // [B][E][KLEN]
    const bf16* __restrict__ Rb,   // [KLEN][E]
    bf16* __restrict__ O)          // [B*S][E]
{
    const int qt = blockIdx.x, h = blockIdx.y, b = blockIdx.z;
    const int q0 = qt * FQ;
    const int t = threadIdx.x;
    const int w = t >> 6, lane = t & 63;
    const int fr = lane & 15, quad = lane >> 4;
    const int qbase = q0 + w * 16;

    __shared__ short Ks[FK][72];
    __shared__ short Vs[64][72];       // [d][k]
    __shared__ short Rs[128][72];      // R band rows jl=0..126 (row 127 pad)
    __shared__ short BDs[4][16][132];  // per-wave BD tile [qw][jl]
    __shared__ short Ps[4][16][72];    // per-wave P

    // Q A-frags straight from global (one-time)
    const short* quptr = (const short*)Qu + ((size_t)(b * S + qbase + fr)) * E + h * DH + quad * 8;
    const frag_ab au0 = *(const frag_ab*)(quptr);
    const frag_ab au1 = *(const frag_ab*)(quptr + 32);
    const short* qvptr = (const short*)Qv + ((size_t)(b * S + qbase + fr)) * E + h * DH + quad * 8;
    const frag_ab av0 = *(const frag_ab*)(qvptr);
    const frag_ab av1 = *(const frag_ab*)(qvptr + 32);

    frag_cd accO[4];
    #pragma unroll
    for (int i = 0; i < 4; ++i) accO[i] = (frag_cd)(0.0f);
    float mrow[4] = {-3.0e38f, -3.0e38f, -3.0e38f, -3.0e38f};
    float lrow[4] = {0.f, 0.f, 0.f, 0.f};

    const int srow = t >> 2, scol = (t & 3) * 16;   // K/V staging
    const int rrow = t >> 1, rcol = (t & 1) * 32;   // R staging (128 rows x 2 halves)
    const short* kg = (const short*)Kb + ((size_t)(b * KLEN + srow)) * E + h * DH + scol;
    const short* vg = (const short*)Vt + ((size_t)(b * E + h * DH + srow)) * KLEN + scol;
    const int ntb0 = 3 - w;            // wave-specific BD j-window: ntb0..ntb0+4

    const int ntiles = 9 + qt;
    for (int kt = 0; kt < ntiles; ++kt) {
        const int k0 = kt * FK;
        __syncthreads();
        {   // stage K[64k][64d] and V^T[64d][64k]
            const short* kp = kg + (size_t)k0 * E;
            *(uint4*)&Ks[srow][scol]     = *(const uint4*)(kp);
            *(uint4*)&Ks[srow][scol + 8] = *(const uint4*)(kp + 8);
            const short* vp = vg + k0;
            *(uint4*)&Vs[srow][scol]     = *(const uint4*)(vp);
            *(uint4*)&Vs[srow][scol + 8] = *(const uint4*)(vp + 8);
        }
        {   // stage R band: jl = j - (k0 + 448 - q0), clamped rows feed masked scores
            int j = k0 + 448 - q0 + rrow; if (j > KLEN - 1) j = KLEN - 1;
            const short* rp = (const short*)Rb + (size_t)j * E + h * DH + rcol;
            *(uint4*)&Rs[rrow][rcol]      = *(const uint4*)(rp);
            *(uint4*)&Rs[rrow][rcol + 8]  = *(const uint4*)(rp + 8);
            *(uint4*)&Rs[rrow][rcol + 16] = *(const uint4*)(rp + 16);
            *(uint4*)&Rs[rrow][rcol + 24] = *(const uint4*)(rp + 24);
        }
        __syncthreads();

        // ---- BD tile: BDs[w][qw][jl] = Qv·R_band^T (wave's 80-col window) ----
        #pragma unroll
        for (int i = 0; i < 5; ++i) {
            const int ntb = ntb0 + i;
            const frag_ab rf0 = *(const frag_ab*)&Rs[ntb * 16 + fr][quad * 8];
            const frag_ab rf1 = *(const frag_ab*)&Rs[ntb * 16 + fr][32 + quad * 8];
            frag_cd z = (frag_cd)(0.0f);
            z = __builtin_amdgcn_mfma_f32_16x16x32_bf16(av0, rf0, z, 0, 0, 0);
            z = __builtin_amdgcn_mfma_f32_16x16x32_bf16(av1, rf1, z, 0, 0, 0);
            #pragma unroll
            for (int r = 0; r < 4; ++r)
                BDs[w][quad * 4 + r][ntb * 16 + fr] = f2bs(z[r]);
        }

        // ---- S = Qu·K^T ----
        frag_cd sc[4];
        #pragma unroll
        for (int nt = 0; nt < 4; ++nt) {
            const frag_ab kf0 = *(const frag_ab*)&Ks[nt * 16 + fr][quad * 8];
            const frag_ab kf1 = *(const frag_ab*)&Ks[nt * 16 + fr][32 + quad * 8];
            frag_cd z = (frag_cd)(0.0f);
            z = __builtin_amdgcn_mfma_f32_16x16x32_bf16(au0, kf0, z, 0, 0, 0);
            z = __builtin_amdgcn_mfma_f32_16x16x32_bf16(au1, kf1, z, 0, 0, 0);
            sc[nt] = z;
        }

        // ---- +BD (from LDS), mask, online softmax per C-row ----
        #pragma unroll
        for (int r = 0; r < 4; ++r) {
            const int qw = quad * 4 + r;
            const int qrow = qbase + qw;
            float sv[4];
            #pragma unroll
            for (int nt = 0; nt < 4; ++nt) {
                const int kcol = k0 + nt * 16 + fr;
                const int jl = nt * 16 + fr + 63 - w * 16 - qw;  // within wave window
                const float bd = bs2f(BDs[w][qw][jl]);
                const float sval = (sc[nt][r] + bd) * 0.125f;
                sv[nt] = (kcol <= MEM + qrow) ? sval : -1e30f;
            }
            float tm = fmaxf(fmaxf(sv[0], sv[1]), fmaxf(sv[2], sv[3]));
            tm = fmaxf(tm, __shfl_xor(tm, 1, 64));
            tm = fmaxf(tm, __shfl_xor(tm, 2, 64));
            tm = fmaxf(tm, __shfl_xor(tm, 4, 64));
            tm = fmaxf(tm, __shfl_xor(tm, 8, 64));
            const float mn = fmaxf(mrow[r], tm);
            const float p0 = __expf(sv[0] - mn), p1 = __expf(sv[1] - mn);
            const float p2 = __expf(sv[2] - mn), p3 = __expf(sv[3] - mn);
            float wsum = p0 + p1 + p2 + p3;
            wsum += __shfl_xor(wsum, 1, 64);
            wsum += __shfl_xor(wsum, 2, 64);
            wsum += __shfl_xor(wsum, 4, 64);
            wsum += __shfl_xor(wsum, 8, 64);
            const float al = __expf(mrow[r] - mn);
            lrow[r] = lrow[r] * al + wsum;
            mrow[r] = mn;
            #pragma unroll
            for (int nt = 0; nt < 4; ++nt) accO[nt][r] *= al;
            Ps[w][qw][fr]      = f2bs(p0);
            Ps[w][qw][16 + fr] = f2bs(p1);
            Ps[w][qw][32 + fr] = f2bs(p2);
            Ps[w][qw][48 + fr] = f2bs(p3);
        }

        // ---- O += P·V (per-wave P; same-wave LDS, DS in-order) ----
        const frag_ab pf0 = *(const frag_ab*)&Ps[w][fr][quad * 8];
        const frag_ab pf1 = *(const frag_ab*)&Ps[w][fr][32 + quad * 8];
        #pragma unroll
        for (int nt = 0; nt < 4; ++nt) {
            const frag_ab vf0 = *(const frag_ab*)&Vs[nt * 16 + fr][quad * 8];
            const frag_ab vf1 = *(const frag_ab*)&Vs[nt * 16 + fr][32 + quad * 8];
            accO[nt] = __builtin_amdgcn_mfma_f32_16x16x32_bf16(pf0, vf0, accO[nt], 0, 0, 0);
            accO[nt] = __builtin_amdgcn_mfma_f32_16x16x32_bf16(pf1, vf1, accO[nt], 0, 0, 0);
        }
    }

    #pragma unroll
    for (int r = 0; r < 4; ++r) {
        const float inv = 1.0f / lrow[r];
        bf16* po = O + ((size_t)(b * S + qbase + quad * 4 + r)) * E + h * DH + fr;
        #pragma unroll
        for (int nt = 0; nt < 4; ++nt)
            po[nt * 16] = __float2bfloat16(accO[nt][r] * inv);
    }
}

extern "C" void kernel_launch(void* const* d_in, const int* in_sizes, int n_in,
                              void* d_out, int out_size, void* d_ws, size_t ws_size,
                              hipStream_t stream)
{
    const float* obs  = (const float*)d_in[0];
    const float* mem  = (const float*)d_in[1];
    // d_in[2] = mask: deterministic (k <= MEM + q), recomputed in-kernel
    const float* Wenc = (const float*)d_in[3];
    const float* benc = (const float*)d_in[4];
    const float* ln1s = (const float*)d_in[5];
    const float* ln1b = (const float*)d_in[6];
    const float* Wq   = (const float*)d_in[7];
    const float* bq   = (const float*)d_in[8];
    const float* Wk   = (const float*)d_in[9];
    const float* bk   = (const float*)d_in[10];
    const float* Wv   = (const float*)d_in[11];
    const float* bv   = (const float*)d_in[12];
    const float* Wr   = (const float*)d_in[13];
    const float* ub   = (const float*)d_in[14];
    const float* vb   = (const float*)d_in[15];
    const float* Wo   = (const float*)d_in[16];
    const float* bo   = (const float*)d_in[17];
    const float* ln2s = (const float*)d_in[18];
    const float* ln2b = (const float*)d_in[19];
    const float* W1   = (const float*)d_in[20];
    const float* b1   = (const float*)d_in[21];
    const float* W2   = (const float*)d_in[22];
    const float* b2   = (const float*)d_in[23];

    // ---- workspace ----
    float* wsf = (float*)d_ws;
    float* X = wsf;                                   // fp32 [B*S*E]
    bf16* wsb = (bf16*)(wsf + (size_t)B * S * E);
    size_t ob = 0;
    bf16* OBSb = wsb + ob; ob += (size_t)B * S * OBS;
    bf16* QNb  = wsb + ob; ob += (size_t)B * S * E;
    bf16* PEb  = wsb + ob; ob += (size_t)KLEN * E;
    bf16* RBb  = wsb + ob; ob += (size_t)KLEN * E;
    bf16* WencT= wsb + ob; ob += (size_t)OBS * E;
    bf16* WqT  = wsb + ob; ob += (size_t)L * E * E;
    bf16* WkvT = wsb + ob; ob += (size_t)L * 2 * E * E;   // [L][1024][512]
    bf16* WrT  = wsb + ob; ob += (size_t)L * E * E;
    bf16* WoT  = wsb + ob; ob += (size_t)L * E * E;
    bf16* W1T  = wsb + ob; ob += (size_t)L * E * E;
    bf16* W2T  = wsb + ob; ob += (size_t)L * E * E;
    bf16* QUb  = wsb + ob; ob += (size_t)B * S * E;
    bf16* QVb  = wsb + ob; ob += (size_t)B * S * E;
    bf16* KBb  = wsb + ob; ob += (size_t)B * KLEN * E;
    bf16* VTb  = wsb + ob; ob += (size_t)B * E * KLEN;
    bf16* OBb  = wsb + ob; ob += (size_t)B * S * E;
    // union: {VKb, VBb} ∪ {HB, FFb} (disjoint lifetimes per layer)
    char* uni = (char*)(wsb + ob);
    bf16*  VKb = (bf16*)uni;                          // [B*KLEN][E] (8 MB) @0
    bf16*  VBb = (bf16*)(uni + ((size_t)8 << 20));    // [B*KLEN][E] (8 MB) @8M
    float* HB  = (float*)uni;                         // [B*S][E] fp32 (8 MB) @0
    bf16*  FFb = (bf16*)(uni + ((size_t)8 << 20));    // [B*S][E] (4 MB) @8M

    // ---- weight transpose+cast ----
    transpose_cast_kernel<<<dim3(E / 32, OBS / 32, 1), 256, 0, stream>>>(Wenc, WencT, OBS, E, OBS * E);
    transpose_cast_kernel<<<dim3(E / 32, E / 32, L), 256, 0, stream>>>(Wq, WqT, E, E, E * E);
    transpose_cast_kernel<<<dim3(E / 32, E / 32, L), 256, 0, stream>>>(Wk, WkvT, E, E, 2 * E * E);
    transpose_cast_kernel<<<dim3(E / 32, E / 32, L), 256, 0, stream>>>(Wv, WkvT + E * E, E, E, 2 * E * E);
    transpose_cast_kernel<<<dim3(E / 32, E / 32, L), 256, 0, stream>>>(Wr, WrT, E, E, E * E);
    transpose_cast_kernel<<<dim3(E / 32, E / 32, L), 256, 0, stream>>>(Wo, WoT, E, E, E * E);
    transpose_cast_kernel<<<dim3(E / 32, E / 32, L), 256, 0, stream>>>(W1, W1T, E, E, E * E);
    transpose_cast_kernel<<<dim3(E / 32, E / 32, L), 256, 0, stream>>>(W2, W2T, E, E, E * E);

    cast_obs_kernel<<<(B * S * OBS) / 256, 256, 0, stream>>>(obs, OBSb);
    pe_kernel<<<(KLEN * E) / 256, 256, 0, stream>>>(PEb);

    // encoder: X = obs @ W_enc + b_enc (fp32)
    mfma_gemm_kernel<<<dim3(E / 128, (B * S) / 128), 256, 0, stream>>>(
        OBSb, WencT, benc, nullptr, nullptr, nullptr, X, nullptr, nullptr,
        B * S, E, OBS, 0, 0);

    for (int li = 0; li < L; ++li) {
        const size_t wOff = (size_t)li * E * E;
        const size_t vOff = (size_t)li * E;

        ln_mem_kernel<<<B * MEM, 256, 0, stream>>>(mem, li, ln1s + vOff, ln1b + vOff, VKb);
        ln_f32_kernel<<<B * S, 256, 0, stream>>>(X, ln1s + vOff, ln1b + vOff, QNb, VKb);

        // Q -> QU/QV (bf16, dual bias)
        mfma_gemm_kernel<<<dim3(E / 128, (B * S) / 128), 256, 0, stream>>>(
            QNb, WqT + wOff, bq + vOff, ub + vOff, vb + vOff, nullptr,
            nullptr, QUb, QVb, B * S, E, E, 0, 1);
        // fused K|V projection (N=1024, split epilogue)
        mfma_gemm_kernel<<<dim3((2 * E) / 128, (B * KLEN) / 128), 256, 0, stream>>>(
            VKb, WkvT + (size_t)li * 2 * E * E, nullptr, bk + vOff, bv + vOff, nullptr,
            nullptr, KBb, VBb, B * KLEN, 2 * E, E, 0, 2);
        // R projection
        mfma_gemm_kernel<<<dim3(E / 128, KLEN / 128), 256, 0, stream>>>(
            PEb, WrT + wOff, nullptr, nullptr, nullptr, nullptr,
            nullptr, RBb, nullptr, KLEN, E, E, 0, 0);

        transpose_v_kernel<<<dim3(KLEN / 64, E / 64, B), 256, 0, stream>>>(VBb, VTb);

        mfma_flash_kernel<<<dim3(S / FQ, H, B), 256, 0, stream>>>(
            QUb, QVb, KBb, VTb, RBb, OBb);

        // HB = X + (O @ Wo + bo)
        mfma_gemm_kernel<<<dim3(E / 128, (B * S) / 128), 256, 0, stream>>>(
            OBb, WoT + wOff, bo + vOff, nullptr, nullptr, X, HB, nullptr, nullptr,
            B * S, E, E, 0, 0);
        ln_f32_kernel<<<B * S, 256, 0, stream>>>(HB, ln2s + vOff, ln2b + vOff, QNb, nullptr);
        // FFb = gelu(hn @ W1 + b1)
        mfma_gemm_kernel<<<dim3(E / 128, (B * S) / 128), 256, 0, stream>>>(
            QNb, W1T + wOff, b1 + vOff, nullptr, nullptr, nullptr,
            nullptr, FFb, nullptr, B * S, E, E, 1, 0);
        // X = FF @ W2 + b2 + HB
        mfma_gemm_kernel<<<dim3(E / 128, (B * S) / 128), 256, 0, stream>>>(
            FFb, W2T + wOff, b2 + vOff, nullptr, nullptr, HB, X, nullptr, nullptr,
            B * S, E, E, 0, 0);
    }

    hipMemcpyAsync(d_out, X, (size_t)B * S * E * sizeof(float),
                   hipMemcpyDeviceToDevice, stream);
}

// Round 7
// 840.874 us; speedup vs baseline: 10.2086x; 1.5796x over previous
//
#include <hip/hip_runtime.h>
#include <hip/hip_bf16.h>
#include <math.h>

#define B     8
#define S     512
#define MEM   512
#define L     4
#define E     512
#define H     8
#define DH    64
#define OBS   128
#define KLEN  1024   // MEM + S
#define FQ    64     // flash: q rows per block
#define FK    64     // flash: k per tile

typedef __hip_bfloat16 bf16;
using frag_ab = __attribute__((ext_vector_type(8))) short;   // 8 bf16 (4 VGPRs)
using frag_cd = __attribute__((ext_vector_type(4))) float;   // 4 fp32 acc

__device__ __forceinline__ float gelu_tanh(float x) {
    return 0.5f * x * (1.0f + tanhf(0.7978845608028654f * (x + 0.044715f * x * x * x)));
}
__device__ __forceinline__ unsigned short f2bs(float x) {
    bf16 h = __float2bfloat16(x); return *(unsigned short*)&h;
}
__device__ __forceinline__ float bs2f(short s) {
    union { unsigned u; float f; } t; t.u = ((unsigned)(unsigned short)s) << 16; return t.f;
}

// ---------------- positional embedding (bf16 out) ----------------------------
__global__ __launch_bounds__(256) void pe_kernel(bf16* __restrict__ pe) {
    const int idx = blockIdx.x * 256 + threadIdx.x;
    const int p = idx >> 9;
    const int j = idx & 511;
    const float pos = (float)(KLEN - p);
    const int m = (j < 256) ? j : (j - 256);
    const float invf = expf(-(float)(2 * m) * (9.210340371976184f / (float)E));
    const float a = pos * invf;
    pe[idx] = __float2bfloat16((j < 256) ? sinf(a) : cosf(a));
}

__global__ __launch_bounds__(256) void cast_obs_kernel(const float* __restrict__ x,
                                                       bf16* __restrict__ o) {
    const int i = blockIdx.x * 256 + threadIdx.x;
    o[i] = __float2bfloat16(x[i]);
}

// ------- generic weight transpose+cast (used for Wenc) -----------------------
__global__ __launch_bounds__(256) void transpose_cast_kernel(
    const float* __restrict__ W, bf16* __restrict__ Wt, int Kd, int Nd)
{
    __shared__ float t[32][33];
    const int bn = blockIdx.x * 32, bk = blockIdx.y * 32;
    const int tx = threadIdx.x & 31, ty = threadIdx.x >> 5;
    #pragma unroll
    for (int r = 0; r < 32; r += 8)
        t[ty + r][tx] = W[(size_t)(bk + ty + r) * Nd + bn + tx];
    __syncthreads();
    #pragma unroll
    for (int r = 0; r < 32; r += 8)
        Wt[(size_t)(bn + ty + r) * Kd + bk + tx] = __float2bfloat16(t[tx][ty + r]);
}

// ------- merged E x E weight transposes: z = which*4 + li --------------------
__global__ __launch_bounds__(256) void transpose_all_kernel(
    const float* __restrict__ Wq, const float* __restrict__ Wk,
    const float* __restrict__ Wv, const float* __restrict__ Wr,
    const float* __restrict__ Wo, const float* __restrict__ W1,
    const float* __restrict__ W2,
    bf16* __restrict__ WqT, bf16* __restrict__ WkvT, bf16* __restrict__ WrT,
    bf16* __restrict__ WoT, bf16* __restrict__ W1T, bf16* __restrict__ W2T)
{
    __shared__ float t[32][33];
    const int z = blockIdx.z, which = z >> 2, li = z & 3;
    const size_t so = (size_t)li * E * E;
    const float* src; bf16* dst;
    switch (which) {
        case 0: src = Wq + so; dst = WqT + so; break;
        case 1: src = Wk + so; dst = WkvT + (size_t)li * 2 * E * E; break;
        case 2: src = Wv + so; dst = WkvT + (size_t)li * 2 * E * E + (size_t)E * E; break;
        case 3: src = Wr + so; dst = WrT + so; break;
        case 4: src = Wo + so; dst = WoT + so; break;
        case 5: src = W1 + so; dst = W1T + so; break;
        default: src = W2 + so; dst = W2T + so; break;
    }
    const int bn = blockIdx.x * 32, bk = blockIdx.y * 32;
    const int tx = threadIdx.x & 31, ty = threadIdx.x >> 5;
    #pragma unroll
    for (int r = 0; r < 32; r += 8)
        t[ty + r][tx] = src[(size_t)(bk + ty + r) * E + bn + tx];
    __syncthreads();
    #pragma unroll
    for (int r = 0; r < 32; r += 8)
        dst[(size_t)(bn + ty + r) * E + bk + tx] = __float2bfloat16(t[tx][ty + r]);
}

// ---------------- V transpose: Vn[B*KLEN][E] bf16 -> Vt[B][E][KLEN] bf16 -----
__global__ __launch_bounds__(256) void transpose_v_kernel(
    const bf16* __restrict__ Vn, bf16* __restrict__ Vt)
{
    __shared__ short ts[64][72];
    const int k0 = blockIdx.x * 64, d0 = blockIdx.y * 64, b = blockIdx.z;
    const int t = threadIdx.x;
    const int r = t >> 2, c = (t & 3) * 16;
    const short* src = (const short*)Vn + ((size_t)(b * KLEN + k0 + r)) * E + d0 + c;
    *(uint4*)&ts[r][c]     = *(const uint4*)(src);
    *(uint4*)&ts[r][c + 8] = *(const uint4*)(src + 8);
    __syncthreads();
    short vals[16];
    #pragma unroll
    for (int i = 0; i < 16; ++i) vals[i] = ts[c + i][r];
    short* dst = (short*)Vt + ((size_t)(b * E + d0 + r)) * KLEN + k0 + c;
    *(uint4*)(dst)     = *(const uint4*)&vals[0];
    *(uint4*)(dst + 8) = *(const uint4*)&vals[8];
}

// ---------------- GEMM tile body: 128m x 64n, BK=32, 4 waves of 64x32 --------
// LDS rows padded to 40 shorts (80B: 16B-aligned, 2-way-max banks).
__device__ __forceinline__ void gemm_body(
    short* As, short* Bs,
    const bf16* __restrict__ A, const bf16* __restrict__ Bt,
    int m0, int n0, int K, int N,
    const float* bias, const float* bias_u, const float* bias_v,
    const float* res, float* Cf, bf16* Cb, bf16* Cb2, int act, int mode)
{
    const int tid = threadIdx.x;
    const int w = tid >> 6, lane = tid & 63;
    const int wm2 = (w >> 1) * 64, wn2 = (w & 1) * 32;
    const int fr = lane & 15, quad = lane >> 4;

    const int arow = tid >> 1, acol = (tid & 1) * 16;
    const int brow = tid >> 2, bcol = (tid & 3) * 8;
    const short* Ag = (const short*)A + (size_t)(m0 + arow) * K + acol;
    const short* Bg = (const short*)Bt + (size_t)(n0 + brow) * K + bcol;
    short* Asw = &As[arow * 40 + acol];
    short* Bsw = &Bs[brow * 40 + bcol];

    frag_cd acc[4][2];
    #pragma unroll
    for (int i = 0; i < 4; ++i)
        #pragma unroll
        for (int j = 0; j < 2; ++j)
            acc[i][j] = (frag_cd)(0.0f);

    for (int k0 = 0; k0 < K; k0 += 32) {
        const uint4 a0 = *(const uint4*)(Ag + k0);
        const uint4 a1 = *(const uint4*)(Ag + k0 + 8);
        const uint4 b0 = *(const uint4*)(Bg + k0);
        __syncthreads();
        *(uint4*)(Asw) = a0; *(uint4*)(Asw + 8) = a1;
        *(uint4*)(Bsw) = b0;
        __syncthreads();
        frag_ab af[4], bfr[2];
        #pragma unroll
        for (int i = 0; i < 4; ++i)
            af[i] = *(const frag_ab*)&As[(wm2 + i * 16 + fr) * 40 + quad * 8];
        #pragma unroll
        for (int j = 0; j < 2; ++j)
            bfr[j] = *(const frag_ab*)&Bs[(wn2 + j * 16 + fr) * 40 + quad * 8];
        #pragma unroll
        for (int i = 0; i < 4; ++i)
            #pragma unroll
            for (int j = 0; j < 2; ++j)
                acc[i][j] = __builtin_amdgcn_mfma_f32_16x16x32_bf16(af[i], bfr[j], acc[i][j], 0, 0, 0);
    }

    #pragma unroll
    for (int i = 0; i < 4; ++i) {
        #pragma unroll
        for (int r = 0; r < 4; ++r) {
            const int m = m0 + wm2 + i * 16 + quad * 4 + r;
            #pragma unroll
            for (int j = 0; j < 2; ++j) {
                const int n = n0 + wn2 + j * 16 + fr;
                float v = acc[i][j][r];
                if (bias) v += bias[n];
                if (act)  v = gelu_tanh(v);
                if (res)  v += res[(size_t)m * N + n];
                if (mode == 2) {
                    if (n < 512) Cb[(size_t)m * 512 + n] = __float2bfloat16(v + bias_u[n]);
                    else Cb2[(size_t)m * 512 + (n - 512)] = __float2bfloat16(v + bias_v[n - 512]);
                } else if (mode == 1) {
                    Cb[(size_t)m * N + n]  = __float2bfloat16(v + bias_u[n]);
                    Cb2[(size_t)m * N + n] = __float2bfloat16(v + bias_v[n]);
                } else {
                    if (Cf) Cf[(size_t)m * N + n] = v;
                    if (Cb) Cb[(size_t)m * N + n] = __float2bfloat16(v);
                }
            }
        }
    }
}

// ---------------- standalone GEMM (encoder / Wo / W1 / W2) -------------------
__global__ __launch_bounds__(256) void mfma_gemm_kernel(
    const bf16* __restrict__ A, const bf16* __restrict__ Bt,
    const float* __restrict__ bias, const float* __restrict__ res,
    float* __restrict__ Cf, bf16* __restrict__ Cb,
    int K, int N, int act)
{
    __shared__ short As[128 * 40];
    __shared__ short Bs[64 * 40];
    gemm_body(As, Bs, A, Bt, blockIdx.y * 128, blockIdx.x * 64, K, N,
              bias, nullptr, nullptr, res, Cf, Cb, nullptr, act, 0);
}

// ---------------- fused Q + KV + R projection (one dispatch) -----------------
// blocks 0..255: Q (M=4096, N=512, mode 1 dual-bias -> QU, QV)
// blocks 256..1279: KV (M=8192, N=1024, mode 2 split -> KB, VB)
// blocks 1280..1343: R (M=1024, N=512, mode 0 -> RB)
__global__ __launch_bounds__(256) void qkvr_kernel(
    const bf16* __restrict__ QN, const bf16* __restrict__ VK,
    const bf16* __restrict__ PE_, const bf16* __restrict__ WqT,
    const bf16* __restrict__ WkvT, const bf16* __restrict__ WrT,
    const float* __restrict__ bq, const float* __restrict__ ub,
    const float* __restrict__ vbias, const float* __restrict__ bk,
    const float* __restrict__ bv,
    bf16* __restrict__ QU, bf16* __restrict__ QV,
    bf16* __restrict__ KB, bf16* __restrict__ VB, bf16* __restrict__ RB)
{
    __shared__ short As[128 * 40];
    __shared__ short Bs[64 * 40];
    const int bid = blockIdx.x;
    if (bid < 256) {
        const int mblk = bid >> 3, nblk = bid & 7;
        gemm_body(As, Bs, QN, WqT, mblk * 128, nblk * 64, E, E,
                  bq, ub, vbias, nullptr, nullptr, QU, QV, 0, 1);
    } else if (bid < 1280) {
        const int id = bid - 256;
        const int mblk = id >> 4, nblk = id & 15;
        gemm_body(As, Bs, VK, WkvT, mblk * 128, nblk * 64, E, 2 * E,
                  nullptr, bk, bv, nullptr, nullptr, KB, VB, 0, 2);
    } else {
        const int id = bid - 1280;
        const int mblk = id >> 3, nblk = id & 7;
        gemm_body(As, Bs, PE_, WrT, mblk * 128, nblk * 64, E, E,
                  nullptr, nullptr, nullptr, nullptr, nullptr, RB, nullptr, 0, 0);
    }
}

// ---------------- merged LN pass 1 (memories + x) ----------------------------
__global__ __launch_bounds__(256) void ln1_kernel(
    const float* __restrict__ mem, const float* __restrict__ X, int li,
    const float* __restrict__ gam, const float* __restrict__ bet,
    bf16* __restrict__ qn, bf16* __restrict__ vkdst)
{
    const int blk = blockIdx.x;
    const int t = threadIdx.x;
    const bool isMem = blk < B * MEM;
    const int rr = isMem ? blk : (blk - B * MEM);
    const float* sp = isMem ? (mem + ((size_t)rr * L + li) * E)
                            : (X + (size_t)rr * E);
    const float x0 = sp[t], x1 = sp[t + 256];
    float s = x0 + x1, ss = fmaf(x0, x0, x1 * x1);
    #pragma unroll
    for (int off = 32; off; off >>= 1) { s += __shfl_down(s, off, 64); ss += __shfl_down(ss, off, 64); }
    __shared__ float tmp[8];
    const int wid = t >> 6, lane = t & 63;
    if (!lane) { tmp[wid] = s; tmp[4 + wid] = ss; }
    __syncthreads();
    s = tmp[0] + tmp[1] + tmp[2] + tmp[3];
    ss = tmp[4] + tmp[5] + tmp[6] + tmp[7];
    const float mean = s * (1.0f / E);
    const float var = ss * (1.0f / E) - mean * mean;
    const float rstd = rsqrtf(var + 1e-6f);
    const float y0 = (x0 - mean) * rstd * gam[t] + bet[t];
    const float y1 = (x1 - mean) * rstd * gam[t + 256] + bet[t + 256];
    const int b = rr >> 9, p = rr & 511;
    if (isMem) {
        bf16* dst = vkdst + ((size_t)b * KLEN + p) * E;
        dst[t] = __float2bfloat16(y0); dst[t + 256] = __float2bfloat16(y1);
    } else {
        qn[(size_t)rr * E + t]       = __float2bfloat16(y0);
        qn[(size_t)rr * E + t + 256] = __float2bfloat16(y1);
        bf16* d2 = vkdst + ((size_t)b * KLEN + MEM + p) * E;
        d2[t] = __float2bfloat16(y0); d2[t + 256] = __float2bfloat16(y1);
    }
}

// ---------------- LN (fp32 src -> bf16 dst), used for ln2 --------------------
__global__ __launch_bounds__(256) void ln_f32_kernel(
    const float* __restrict__ src,
    const float* __restrict__ gam, const float* __restrict__ bet,
    bf16* __restrict__ dst1)
{
    const int rr = blockIdx.x;
    const int t = threadIdx.x;
    const float* sp = src + (size_t)rr * E;
    const float x0 = sp[t], x1 = sp[t + 256];
    float s = x0 + x1, ss = fmaf(x0, x0, x1 * x1);
    #pragma unroll
    for (int off = 32; off; off >>= 1) { s += __shfl_down(s, off, 64); ss += __shfl_down(ss, off, 64); }
    __shared__ float tmp[8];
    const int wid = t >> 6, lane = t & 63;
    if (!lane) { tmp[wid] = s; tmp[4 + wid] = ss; }
    __syncthreads();
    s = tmp[0] + tmp[1] + tmp[2] + tmp[3];
    ss = tmp[4] + tmp[5] + tmp[6] + tmp[7];
    const float mean = s * (1.0f / E);
    const float var = ss * (1.0f / E) - mean * mean;
    const float rstd = rsqrtf(var + 1e-6f);
    dst1[(size_t)rr * E + t]       = __float2bfloat16((x0 - mean) * rstd * gam[t] + bet[t]);
    dst1[(size_t)rr * E + t + 256] = __float2bfloat16((x1 - mean) * rstd * gam[t + 256] + bet[t + 256]);
}

// ---------------- MFMA flash attention (in-LDS BD, circular R) ---------------
// block=(qt,h,b) with qt work-balance swizzle; 64 q rows (4 waves x 16).
// score = (Qu·K^T + Qv·R[k+511-q]) * 0.125, mask k <= 512+q.
__global__ __launch_bounds__(256) void mfma_flash_kernel(
    const bf16* __restrict__ Qu,   // [B*S][E]
    const bf16* __restrict__ Qv,   // [B*S][E]
    const bf16* __restrict__ Kb,   // [B*KLEN][E]
    const bf16* __restrict__ Vt,   // [B][E][KLEN]
    const bf16* __restrict__ Rb,   // [KLEN][E]
    bf16* __restrict__ O)          // [B*S][E]
{
    const int qphys = blockIdx.x, h = blockIdx.y, b = blockIdx.z;
    // pair long and short blocks: (0,7),(1,6),(2,5),(3,4) -> equal 25-tile pairs
    const int qt = (qphys & 1) ? (7 - (qphys >> 1)) : (qphys >> 1);
    const int q0 = qt * FQ;
    const int t = threadIdx.x;
    const int w = t >> 6, lane = t & 63;
    const int fr = lane & 15, quad = lane >> 4;
    const int qbase = q0 + w * 16;

    __shared__ short Ks[FK][72];
    __shared__ short Vs[64][72];       // [d][k]
    __shared__ short Rs[128][72];      // circular R band, slot = j & 127
    __shared__ short BDs[4][80][20];   // per-wave BD transposed [jlr][qw]
    __shared__ short Ps[4][16][72];    // per-wave P

    // Q A-frags straight from global (one-time)
    const short* quptr = (const short*)Qu + ((size_t)(b * S + qbase + fr)) * E + h * DH + quad * 8;
    const frag_ab au0 = *(const frag_ab*)(quptr);
    const frag_ab au1 = *(const frag_ab*)(quptr + 32);
    const short* qvptr = (const short*)Qv + ((size_t)(b * S + qbase + fr)) * E + h * DH + quad * 8;
    const frag_ab av0 = *(const frag_ab*)(qvptr);
    const frag_ab av1 = *(const frag_ab*)(qvptr + 32);

    frag_cd accO[4];
    #pragma unroll
    for (int i = 0; i < 4; ++i) accO[i] = (frag_cd)(0.0f);
    float mrow[4] = {-3.0e38f, -3.0e38f, -3.0e38f, -3.0e38f};
    float lrow[4] = {0.f, 0.f, 0.f, 0.f};

    const int srow = t >> 2, scol = (t & 3) * 16;   // K/V staging
    const short* kg = (const short*)Kb + ((size_t)(b * KLEN + srow)) * E + h * DH + scol;
    const short* vg = (const short*)Vt + ((size_t)(b * E + h * DH + srow)) * KLEN + scol;
    const int ntb0 = 3 - w;            // wave BD window: n-tiles ntb0..ntb0+4
    const int b0 = 448 - q0;           // R band origin at kt=0 (0..448)

    // ---- initial R window: rows j = b0 .. b0+127 (always <= 575, no clamp) --
    {
        const int rr = t >> 1, rc = (t & 1) * 32;
        const int j = b0 + rr;
        const int slot = j & 127;
        const short* rp = (const short*)Rb + (size_t)j * E + h * DH + rc;
        *(uint4*)&Rs[slot][rc]      = *(const uint4*)(rp);
        *(uint4*)&Rs[slot][rc + 8]  = *(const uint4*)(rp + 8);
        *(uint4*)&Rs[slot][rc + 16] = *(const uint4*)(rp + 16);
        *(uint4*)&Rs[slot][rc + 24] = *(const uint4*)(rp + 24);
    }

    const int ntiles = 9 + qt;
    for (int kt = 0; kt < ntiles; ++kt) {
        const int k0 = kt * FK;
        __syncthreads();
        {   // stage K[64k][64d] and V^T[64d][64k]
            const short* kp = kg + (size_t)k0 * E;
            *(uint4*)&Ks[srow][scol]     = *(const uint4*)(kp);
            *(uint4*)&Ks[srow][scol + 8] = *(const uint4*)(kp + 8);
            const short* vp = vg + k0;
            *(uint4*)&Vs[srow][scol]     = *(const uint4*)(vp);
            *(uint4*)&Vs[srow][scol + 8] = *(const uint4*)(vp + 8);
        }
        if (kt >= 1) {   // slide R window: load 64 new rows
            const int r64 = t >> 2, rc = (t & 3) * 16;
            int j = b0 + 64 * kt + 64 + r64;
            const int slot = j & 127;
            if (j > KLEN - 1) j = KLEN - 1;   // clamped rows feed masked scores only
            const short* rp = (const short*)Rb + (size_t)j * E + h * DH + rc;
            *(uint4*)&Rs[slot][rc]     = *(const uint4*)(rp);
            *(uint4*)&Rs[slot][rc + 8] = *(const uint4*)(rp + 8);
        }
        __syncthreads();

        const int roff = (b0 + 64 * kt) & 127;   // band start slot

        // ---- BD tile: BDs[w][jlr][qw] = Qv·R_band^T (wave's 80-col window) --
        #pragma unroll
        for (int i = 0; i < 5; ++i) {
            const int ntb = ntb0 + i;
            const int slot = (roff + ntb * 16 + fr) & 127;
            const frag_ab rf0 = *(const frag_ab*)&Rs[slot][quad * 8];
            const frag_ab rf1 = *(const frag_ab*)&Rs[slot][32 + quad * 8];
            frag_cd z = (frag_cd)(0.0f);
            z = __builtin_amdgcn_mfma_f32_16x16x32_bf16(av0, rf0, z, 0, 0, 0);
            z = __builtin_amdgcn_mfma_f32_16x16x32_bf16(av1, rf1, z, 0, 0, 0);
            union { uint2 u; unsigned short sh[4]; } pk;
            pk.sh[0] = f2bs(z[0]); pk.sh[1] = f2bs(z[1]);
            pk.sh[2] = f2bs(z[2]); pk.sh[3] = f2bs(z[3]);
            *(uint2*)&BDs[w][i * 16 + fr][quad * 4] = pk.u;
        }

        // ---- S = Qu·K^T ----
        frag_cd sc[4];
        #pragma unroll
        for (int nt = 0; nt < 4; ++nt) {
            const frag_ab kf0 = *(const frag_ab*)&Ks[nt * 16 + fr][quad * 8];
            const frag_ab kf1 = *(const frag_ab*)&Ks[nt * 16 + fr][32 + quad * 8];
            frag_cd z = (frag_cd)(0.0f);
            z = __builtin_amdgcn_mfma_f32_16x16x32_bf16(au0, kf0, z, 0, 0, 0);
            z = __builtin_amdgcn_mfma_f32_16x16x32_bf16(au1, kf1, z, 0, 0, 0);
            sc[nt] = z;
        }

        // ---- +BD (from LDS), mask, online softmax per C-row ----
        #pragma unroll
        for (int r = 0; r < 4; ++r) {
            const int qw = quad * 4 + r;
            const int qrow = qbase + qw;
            float sv[4];
            #pragma unroll
            for (int nt = 0; nt < 4; ++nt) {
                const int kcol = k0 + nt * 16 + fr;
                const int jlr = nt * 16 + fr + 15 - qw;   // 0..78
                const float bd = bs2f(BDs[w][jlr][qw]);
                const float sval = (sc[nt][r] + bd) * 0.125f;
                sv[nt] = (kcol <= MEM + qrow) ? sval : -1e30f;
            }
            float tm = fmaxf(fmaxf(sv[0], sv[1]), fmaxf(sv[2], sv[3]));
            tm = fmaxf(tm, __shfl_xor(tm, 1, 64));
            tm = fmaxf(tm, __shfl_xor(tm, 2, 64));
            tm = fmaxf(tm, __shfl_xor(tm, 4, 64));
            tm = fmaxf(tm, __shfl_xor(tm, 8, 64));
            const float mn = fmaxf(mrow[r], tm);
            const float p0 = __expf(sv[0] - mn), p1 = __expf(sv[1] - mn);
            const float p2 = __expf(sv[2] - mn), p3 = __expf(sv[3] - mn);
            float wsum = p0 + p1 + p2 + p3;
            wsum += __shfl_xor(wsum, 1, 64);
            wsum += __shfl_xor(wsum, 2, 64);
            wsum += __shfl_xor(wsum, 4, 64);
            wsum += __shfl_xor(wsum, 8, 64);
            const float al = __expf(mrow[r] - mn);
            lrow[r] = lrow[r] * al + wsum;
            mrow[r] = mn;
            #pragma unroll
            for (int nt = 0; nt < 4; ++nt) accO[nt][r] *= al;
            Ps[w][qw][fr]      = (short)f2bs(p0);
            Ps[w][qw][16 + fr] = (short)f2bs(p1);
            Ps[w][qw][32 + fr] = (short)f2bs(p2);
            Ps[w][qw][48 + fr] = (short)f2bs(p3);
        }

        // ---- O += P·V (per-wave P; same-wave LDS, DS in-order) ----
        const frag_ab pf0 = *(const frag_ab*)&Ps[w][fr][quad * 8];
        const frag_ab pf1 = *(const frag_ab*)&Ps[w][fr][32 + quad * 8];
        #pragma unroll
        for (int nt = 0; nt < 4; ++nt) {
            const frag_ab vf0 = *(const frag_ab*)&Vs[nt * 16 + fr][quad * 8];
            const frag_ab vf1 = *(const frag_ab*)&Vs[nt * 16 + fr][32 + quad * 8];
            accO[nt] = __builtin_amdgcn_mfma_f32_16x16x32_bf16(pf0, vf0, accO[nt], 0, 0, 0);
            accO[nt] = __builtin_amdgcn_mfma_f32_16x16x32_bf16(pf1, vf1, accO[nt], 0, 0, 0);
        }
    }

    #pragma unroll
    for (int r = 0; r < 4; ++r) {
        const float inv = 1.0f / lrow[r];
        bf16* po = O + ((size_t)(b * S + qbase + quad * 4 + r)) * E + h * DH + fr;
        #pragma unroll
        for (int nt = 0; nt < 4; ++nt)
            po[nt * 16] = __float2bfloat16(accO[nt][r] * inv);
    }
}

extern "C" void kernel_launch(void* const* d_in, const int* in_sizes, int n_in,
                              void* d_out, int out_size, void* d_ws, size_t ws_size,
                              hipStream_t stream)
{
    const float* obs  = (const float*)d_in[0];
    const float* mem  = (const float*)d_in[1];
    // d_in[2] = mask: deterministic (k <= MEM + q), recomputed in-kernel
    const float* Wenc = (const float*)d_in[3];
    const float* benc = (const float*)d_in[4];
    const float* ln1s = (const float*)d_in[5];
    const float* ln1b = (const float*)d_in[6];
    const float* Wq   = (const float*)d_in[7];
    const float* bq   = (const float*)d_in[8];
    const float* Wk   = (const float*)d_in[9];
    const float* bk   = (const float*)d_in[10];
    const float* Wv   = (const float*)d_in[11];
    const float* bv   = (const float*)d_in[12];
    const float* Wr   = (const float*)d_in[13];
    const float* ub   = (const float*)d_in[14];
    const float* vb   = (const float*)d_in[15];
    const float* Wo   = (const float*)d_in[16];
    const float* bo   = (const float*)d_in[17];
    const float* ln2s = (const float*)d_in[18];
    const float* ln2b = (const float*)d_in[19];
    const float* W1   = (const float*)d_in[20];
    const float* b1   = (const float*)d_in[21];
    const float* W2   = (const float*)d_in[22];
    const float* b2   = (const float*)d_in[23];

    // ---- workspace ----
    float* wsf = (float*)d_ws;
    float* X = wsf;                                   // fp32 [B*S*E]
    bf16* wsb = (bf16*)(wsf + (size_t)B * S * E);
    size_t ob = 0;
    bf16* OBSb = wsb + ob; ob += (size_t)B * S * OBS;
    bf16* QNb  = wsb + ob; ob += (size_t)B * S * E;
    bf16* PEb  = wsb + ob; ob += (size_t)KLEN * E;
    bf16* RBb  = wsb + ob; ob += (size_t)KLEN * E;
    bf16* WencT= wsb + ob; ob += (size_t)OBS * E;
    bf16* WqT  = wsb + ob; ob += (size_t)L * E * E;
    bf16* WkvT = wsb + ob; ob += (size_t)L * 2 * E * E;   // [L][1024][512]
    bf16* WrT  = wsb + ob; ob += (size_t)L * E * E;
    bf16* WoT  = wsb + ob; ob += (size_t)L * E * E;
    bf16* W1T  = wsb + ob; ob += (size_t)L * E * E;
    bf16* W2T  = wsb + ob; ob += (size_t)L * E * E;
    bf16* QUb  = wsb + ob; ob += (size_t)B * S * E;
    bf16* QVb  = wsb + ob; ob += (size_t)B * S * E;
    bf16* KBb  = wsb + ob; ob += (size_t)B * KLEN * E;
    bf16* VTb  = wsb + ob; ob += (size_t)B * E * KLEN;
    bf16* OBb  = wsb + ob; ob += (size_t)B * S * E;
    // union: {VKb, VBb} ∪ {HB, FFb} (disjoint lifetimes per layer)
    char* uni = (char*)(wsb + ob);
    bf16*  VKb = (bf16*)uni;                          // [B*KLEN][E] (8 MB) @0
    bf16*  VBb = (bf16*)(uni + ((size_t)8 << 20));    // [B*KLEN][E] (8 MB) @8M
    float* HB  = (float*)uni;                         // [B*S][E] fp32 (8 MB) @0
    bf16*  FFb = (bf16*)(uni + ((size_t)8 << 20));    // [B*S][E] (4 MB) @8M

    // ---- setup: weight transposes (merged), casts, pe ----
    transpose_all_kernel<<<dim3(E / 32, E / 32, 28), 256, 0, stream>>>(
        Wq, Wk, Wv, Wr, Wo, W1, W2, WqT, WkvT, WrT, WoT, W1T, W2T);
    transpose_cast_kernel<<<dim3(E / 32, OBS / 32, 1), 256, 0, stream>>>(Wenc, WencT, OBS, E);
    cast_obs_kernel<<<(B * S * OBS) / 256, 256, 0, stream>>>(obs, OBSb);
    pe_kernel<<<(KLEN * E) / 256, 256, 0, stream>>>(PEb);

    // encoder: X = obs @ W_enc + b_enc (fp32)
    mfma_gemm_kernel<<<dim3(E / 64, (B * S) / 128), 256, 0, stream>>>(
        OBSb, WencT, benc, nullptr, X, nullptr, OBS, E, 0);

    for (int li = 0; li < L; ++li) {
        const size_t wOff = (size_t)li * E * E;
        const size_t vOff = (size_t)li * E;

        ln1_kernel<<<2 * B * S, 256, 0, stream>>>(
            mem, X, li, ln1s + vOff, ln1b + vOff, QNb, VKb);

        qkvr_kernel<<<1344, 256, 0, stream>>>(
            QNb, VKb, PEb, WqT + wOff, WkvT + (size_t)li * 2 * E * E, WrT + wOff,
            bq + vOff, ub + vOff, vb + vOff, bk + vOff, bv + vOff,
            QUb, QVb, KBb, VBb, RBb);

        transpose_v_kernel<<<dim3(KLEN / 64, E / 64, B), 256, 0, stream>>>(VBb, VTb);

        mfma_flash_kernel<<<dim3(S / FQ, H, B), 256, 0, stream>>>(
            QUb, QVb, KBb, VTb, RBb, OBb);

        // HB = X + (O @ Wo + bo)
        mfma_gemm_kernel<<<dim3(E / 64, (B * S) / 128), 256, 0, stream>>>(
            OBb, WoT + wOff, bo + vOff, X, HB, nullptr, E, E, 0);
        ln_f32_kernel<<<B * S, 256, 0, stream>>>(HB, ln2s + vOff, ln2b + vOff, QNb);
        // FFb = gelu(hn @ W1 + b1)
        mfma_gemm_kernel<<<dim3(E / 64, (B * S) / 128), 256, 0, stream>>>(
            QNb, W1T + wOff, b1 + vOff, nullptr, nullptr, FFb, E, E, 1);
        // X = FF @ W2 + b2 + HB
        mfma_gemm_kernel<<<dim3(E / 64, (B * S) / 128), 256, 0, stream>>>(
            FFb, W2T + wOff, b2 + vOff, HB, X, nullptr, E, E, 0);
    }

    hipMemcpyAsync(d_out, X, (size_t)B * S * E * sizeof(float),
                   hipMemcpyDeviceToDevice, stream);
}

// Round 8
// 824.464 us; speedup vs baseline: 10.4118x; 1.0199x over previous
//
#include <hip/hip_runtime.h>
#include <hip/hip_bf16.h>
#include <math.h>

#define B     8
#define S     512
#define MEM   512
#define L     4
#define E     512
#define H     8
#define DH    64
#define OBS   128
#define KLEN  1024   // MEM + S
#define FQ    64     // flash: q rows per block
#define FK    64     // flash: k per tile

typedef __hip_bfloat16 bf16;
using frag_ab = __attribute__((ext_vector_type(8))) short;   // 8 bf16 (4 VGPRs)
using frag_cd = __attribute__((ext_vector_type(4))) float;   // 4 fp32 acc

__device__ __forceinline__ float gelu_tanh(float x) {
    return 0.5f * x * (1.0f + tanhf(0.7978845608028654f * (x + 0.044715f * x * x * x)));
}
__device__ __forceinline__ unsigned short f2bs(float x) {
    bf16 h = __float2bfloat16(x); return *(unsigned short*)&h;
}
__device__ __forceinline__ float bs2f(short s) {
    union { unsigned u; float f; } t; t.u = ((unsigned)(unsigned short)s) << 16; return t.f;
}

// ---------------- merged setup: obs cast + positional embedding --------------
__global__ __launch_bounds__(256) void setup_kernel(
    const float* __restrict__ obs, bf16* __restrict__ obsb, bf16* __restrict__ pe)
{
    const int i = blockIdx.x * 256 + threadIdx.x;
    if (i < B * S * OBS) {
        obsb[i] = __float2bfloat16(obs[i]);
    } else {
        const int idx = i - B * S * OBS;
        const int p = idx >> 9;
        const int j = idx & 511;
        const float pos = (float)(KLEN - p);
        const int m = (j < 256) ? j : (j - 256);
        const float invf = expf(-(float)(2 * m) * (9.210340371976184f / (float)E));
        const float a = pos * invf;
        pe[idx] = __float2bfloat16((j < 256) ? sinf(a) : cosf(a));
    }
}

// ------- merged weight transposes: z = which*4 + li; z==28 -> Wenc -----------
__global__ __launch_bounds__(256) void transpose_all_kernel(
    const float* __restrict__ Wq, const float* __restrict__ Wk,
    const float* __restrict__ Wv, const float* __restrict__ Wr,
    const float* __restrict__ Wo, const float* __restrict__ W1,
    const float* __restrict__ W2, const float* __restrict__ Wenc,
    bf16* __restrict__ WqT, bf16* __restrict__ WkvT, bf16* __restrict__ WrT,
    bf16* __restrict__ WoT, bf16* __restrict__ W1T, bf16* __restrict__ W2T,
    bf16* __restrict__ WencT)
{
    __shared__ float t[32][33];
    const int z = blockIdx.z;
    const int bn = blockIdx.x * 32, bk = blockIdx.y * 32;
    const int tx = threadIdx.x & 31, ty = threadIdx.x >> 5;
    if (z == 28) {                         // Wenc: [OBS][E] -> [E][OBS]
        if (blockIdx.y >= OBS / 32) return;
        #pragma unroll
        for (int r = 0; r < 32; r += 8)
            t[ty + r][tx] = Wenc[(size_t)(bk + ty + r) * E + bn + tx];
        __syncthreads();
        #pragma unroll
        for (int r = 0; r < 32; r += 8)
            WencT[(size_t)(bn + ty + r) * OBS + bk + tx] = __float2bfloat16(t[tx][ty + r]);
        return;
    }
    const int which = z >> 2, li = z & 3;
    const size_t so = (size_t)li * E * E;
    const float* src; bf16* dst;
    switch (which) {
        case 0: src = Wq + so; dst = WqT + so; break;
        case 1: src = Wk + so; dst = WkvT + (size_t)li * 2 * E * E; break;
        case 2: src = Wv + so; dst = WkvT + (size_t)li * 2 * E * E + (size_t)E * E; break;
        case 3: src = Wr + so; dst = WrT + so; break;
        case 4: src = Wo + so; dst = WoT + so; break;
        case 5: src = W1 + so; dst = W1T + so; break;
        default: src = W2 + so; dst = W2T + so; break;
    }
    #pragma unroll
    for (int r = 0; r < 32; r += 8)
        t[ty + r][tx] = src[(size_t)(bk + ty + r) * E + bn + tx];
    __syncthreads();
    #pragma unroll
    for (int r = 0; r < 32; r += 8)
        dst[(size_t)(bn + ty + r) * E + bk + tx] = __float2bfloat16(t[tx][ty + r]);
}

// ---------------- V transpose: Vn[B*KLEN][E] bf16 -> Vt[B][E][KLEN] bf16 -----
__global__ __launch_bounds__(256) void transpose_v_kernel(
    const bf16* __restrict__ Vn, bf16* __restrict__ Vt)
{
    __shared__ short ts[64][72];
    const int k0 = blockIdx.x * 64, d0 = blockIdx.y * 64, b = blockIdx.z;
    const int t = threadIdx.x;
    const int r = t >> 2, c = (t & 3) * 16;
    const short* src = (const short*)Vn + ((size_t)(b * KLEN + k0 + r)) * E + d0 + c;
    *(uint4*)&ts[r][c]     = *(const uint4*)(src);
    *(uint4*)&ts[r][c + 8] = *(const uint4*)(src + 8);
    __syncthreads();
    short vals[16];
    #pragma unroll
    for (int i = 0; i < 16; ++i) vals[i] = ts[c + i][r];
    short* dst = (short*)Vt + ((size_t)(b * E + d0 + r)) * KLEN + k0 + c;
    *(uint4*)(dst)     = *(const uint4*)&vals[0];
    *(uint4*)(dst + 8) = *(const uint4*)&vals[8];
}

// ---------------- GEMM tile body: 128m x 64n, BK=64, 4 waves of 64x32 --------
// 16 MFMA + 12 frag reads + 6 staging stores per barrier pair.
__device__ __forceinline__ void gemm_body(
    short* As, short* Bs,
    const bf16* __restrict__ A, const bf16* __restrict__ Bt,
    int m0, int n0, int K, int N,
    const float* bias, const float* bias_u, const float* bias_v,
    const float* res, float* Cf, bf16* Cb, bf16* Cb2, int act, int mode)
{
    const int tid = threadIdx.x;
    const int w = tid >> 6, lane = tid & 63;
    const int wm2 = (w >> 1) * 64, wn2 = (w & 1) * 32;
    const int fr = lane & 15, quad = lane >> 4;

    const int arow = tid >> 1, acol = (tid & 1) * 32;
    const int brow = tid >> 2, bcol = (tid & 3) * 16;
    const short* Ag = (const short*)A + (size_t)(m0 + arow) * K + acol;
    const short* Bg = (const short*)Bt + (size_t)(n0 + brow) * K + bcol;
    short* Asw = &As[arow * 72 + acol];
    short* Bsw = &Bs[brow * 72 + bcol];

    frag_cd acc[4][2];
    #pragma unroll
    for (int i = 0; i < 4; ++i)
        #pragma unroll
        for (int j = 0; j < 2; ++j)
            acc[i][j] = (frag_cd)(0.0f);

    for (int k0 = 0; k0 < K; k0 += 64) {
        const uint4 a0 = *(const uint4*)(Ag + k0);
        const uint4 a1 = *(const uint4*)(Ag + k0 + 8);
        const uint4 a2 = *(const uint4*)(Ag + k0 + 16);
        const uint4 a3 = *(const uint4*)(Ag + k0 + 24);
        const uint4 b0 = *(const uint4*)(Bg + k0);
        const uint4 b1 = *(const uint4*)(Bg + k0 + 8);
        __syncthreads();
        *(uint4*)(Asw) = a0; *(uint4*)(Asw + 8) = a1;
        *(uint4*)(Asw + 16) = a2; *(uint4*)(Asw + 24) = a3;
        *(uint4*)(Bsw) = b0; *(uint4*)(Bsw + 8) = b1;
        __syncthreads();
        #pragma unroll
        for (int kh = 0; kh < 2; ++kh) {
            frag_ab af[4], bfr[2];
            #pragma unroll
            for (int i = 0; i < 4; ++i)
                af[i] = *(const frag_ab*)&As[(wm2 + i * 16 + fr) * 72 + kh * 32 + quad * 8];
            #pragma unroll
            for (int j = 0; j < 2; ++j)
                bfr[j] = *(const frag_ab*)&Bs[(wn2 + j * 16 + fr) * 72 + kh * 32 + quad * 8];
            #pragma unroll
            for (int i = 0; i < 4; ++i)
                #pragma unroll
                for (int j = 0; j < 2; ++j)
                    acc[i][j] = __builtin_amdgcn_mfma_f32_16x16x32_bf16(af[i], bfr[j], acc[i][j], 0, 0, 0);
        }
    }

    #pragma unroll
    for (int i = 0; i < 4; ++i) {
        #pragma unroll
        for (int r = 0; r < 4; ++r) {
            const int m = m0 + wm2 + i * 16 + quad * 4 + r;
            #pragma unroll
            for (int j = 0; j < 2; ++j) {
                const int n = n0 + wn2 + j * 16 + fr;
                float v = acc[i][j][r];
                if (bias) v += bias[n];
                if (act)  v = gelu_tanh(v);
                if (res)  v += res[(size_t)m * N + n];
                if (mode == 2) {
                    if (n < 512) Cb[(size_t)m * 512 + n] = __float2bfloat16(v + bias_u[n]);
                    else Cb2[(size_t)m * 512 + (n - 512)] = __float2bfloat16(v + bias_v[n - 512]);
                } else if (mode == 1) {
                    Cb[(size_t)m * N + n]  = __float2bfloat16(v + bias_u[n]);
                    Cb2[(size_t)m * N + n] = __float2bfloat16(v + bias_v[n]);
                } else {
                    if (Cf) Cf[(size_t)m * N + n] = v;
                    if (Cb) Cb[(size_t)m * N + n] = __float2bfloat16(v);
                }
            }
        }
    }
}

// ---------------- standalone GEMM (encoder / Wo / W1 / W2) -------------------
__global__ __launch_bounds__(256) void mfma_gemm_kernel(
    const bf16* __restrict__ A, const bf16* __restrict__ Bt,
    const float* __restrict__ bias, const float* __restrict__ res,
    float* __restrict__ Cf, bf16* __restrict__ Cb,
    int K, int N, int act)
{
    __shared__ short As[128 * 72];
    __shared__ short Bs[64 * 72];
    gemm_body(As, Bs, A, Bt, blockIdx.y * 128, blockIdx.x * 64, K, N,
              bias, nullptr, nullptr, res, Cf, Cb, nullptr, act, 0);
}

// ---------------- fused Q + KV + R projection (one dispatch) -----------------
// blocks 0..255: Q (M=4096, N=512, mode 1 dual-bias -> QU, QV)
// blocks 256..1279: KV (M=8192, N=1024, mode 2 split -> KB, VB)
// blocks 1280..1343: R (M=1024, N=512, mode 0 -> RB)
__global__ __launch_bounds__(256) void qkvr_kernel(
    const bf16* __restrict__ QN, const bf16* __restrict__ VK,
    const bf16* __restrict__ PE_, const bf16* __restrict__ WqT,
    const bf16* __restrict__ WkvT, const bf16* __restrict__ WrT,
    const float* __restrict__ bq, const float* __restrict__ ub,
    const float* __restrict__ vbias, const float* __restrict__ bk,
    const float* __restrict__ bv,
    bf16* __restrict__ QU, bf16* __restrict__ QV,
    bf16* __restrict__ KB, bf16* __restrict__ VB, bf16* __restrict__ RB)
{
    __shared__ short As[128 * 72];
    __shared__ short Bs[64 * 72];
    const int bid = blockIdx.x;
    if (bid < 256) {
        const int mblk = bid >> 3, nblk = bid & 7;
        gemm_body(As, Bs, QN, WqT, mblk * 128, nblk * 64, E, E,
                  bq, ub, vbias, nullptr, nullptr, QU, QV, 0, 1);
    } else if (bid < 1280) {
        const int id = bid - 256;
        const int mblk = id >> 4, nblk = id & 15;
        gemm_body(As, Bs, VK, WkvT, mblk * 128, nblk * 64, E, 2 * E,
                  nullptr, bk, bv, nullptr, nullptr, KB, VB, 0, 2);
    } else {
        const int id = bid - 1280;
        const int mblk = id >> 3, nblk = id & 7;
        gemm_body(As, Bs, PE_, WrT, mblk * 128, nblk * 64, E, E,
                  nullptr, nullptr, nullptr, nullptr, nullptr, RB, nullptr, 0, 0);
    }
}

// ---------------- merged LN pass 1 (memories + x) ----------------------------
__global__ __launch_bounds__(256) void ln1_kernel(
    const float* __restrict__ mem, const float* __restrict__ X, int li,
    const float* __restrict__ gam, const float* __restrict__ bet,
    bf16* __restrict__ qn, bf16* __restrict__ vkdst)
{
    const int blk = blockIdx.x;
    const int t = threadIdx.x;
    const bool isMem = blk < B * MEM;
    const int rr = isMem ? blk : (blk - B * MEM);
    const float* sp = isMem ? (mem + ((size_t)rr * L + li) * E)
                            : (X + (size_t)rr * E);
    const float x0 = sp[t], x1 = sp[t + 256];
    float s = x0 + x1, ss = fmaf(x0, x0, x1 * x1);
    #pragma unroll
    for (int off = 32; off; off >>= 1) { s += __shfl_down(s, off, 64); ss += __shfl_down(ss, off, 64); }
    __shared__ float tmp[8];
    const int wid = t >> 6, lane = t & 63;
    if (!lane) { tmp[wid] = s; tmp[4 + wid] = ss; }
    __syncthreads();
    s = tmp[0] + tmp[1] + tmp[2] + tmp[3];
    ss = tmp[4] + tmp[5] + tmp[6] + tmp[7];
    const float mean = s * (1.0f / E);
    const float var = ss * (1.0f / E) - mean * mean;
    const float rstd = rsqrtf(var + 1e-6f);
    const float y0 = (x0 - mean) * rstd * gam[t] + bet[t];
    const float y1 = (x1 - mean) * rstd * gam[t + 256] + bet[t + 256];
    const int b = rr >> 9, p = rr & 511;
    if (isMem) {
        bf16* dst = vkdst + ((size_t)b * KLEN + p) * E;
        dst[t] = __float2bfloat16(y0); dst[t + 256] = __float2bfloat16(y1);
    } else {
        qn[(size_t)rr * E + t]       = __float2bfloat16(y0);
        qn[(size_t)rr * E + t + 256] = __float2bfloat16(y1);
        bf16* d2 = vkdst + ((size_t)b * KLEN + MEM + p) * E;
        d2[t] = __float2bfloat16(y0); d2[t + 256] = __float2bfloat16(y1);
    }
}

// ---------------- LN (fp32 src -> bf16 dst), used for ln2 --------------------
__global__ __launch_bounds__(256) void ln_f32_kernel(
    const float* __restrict__ src,
    const float* __restrict__ gam, const float* __restrict__ bet,
    bf16* __restrict__ dst1)
{
    const int rr = blockIdx.x;
    const int t = threadIdx.x;
    const float* sp = src + (size_t)rr * E;
    const float x0 = sp[t], x1 = sp[t + 256];
    float s = x0 + x1, ss = fmaf(x0, x0, x1 * x1);
    #pragma unroll
    for (int off = 32; off; off >>= 1) { s += __shfl_down(s, off, 64); ss += __shfl_down(ss, off, 64); }
    __shared__ float tmp[8];
    const int wid = t >> 6, lane = t & 63;
    if (!lane) { tmp[wid] = s; tmp[4 + wid] = ss; }
    __syncthreads();
    s = tmp[0] + tmp[1] + tmp[2] + tmp[3];
    ss = tmp[4] + tmp[5] + tmp[6] + tmp[7];
    const float mean = s * (1.0f / E);
    const float var = ss * (1.0f / E) - mean * mean;
    const float rstd = rsqrtf(var + 1e-6f);
    dst1[(size_t)rr * E + t]       = __float2bfloat16((x0 - mean) * rstd * gam[t] + bet[t]);
    dst1[(size_t)rr * E + t + 256] = __float2bfloat16((x1 - mean) * rstd * gam[t + 256] + bet[t + 256]);
}

// ---------------- MFMA flash attention (in-LDS BD, circular R) ---------------
// block=(qt,h,b) with qt work-balance swizzle; 64 q rows (4 waves x 16).
// score = (Qu·K^T + Qv·R[k+511-q]) * 0.125, mask k <= 512+q.
__global__ __launch_bounds__(256) void mfma_flash_kernel(
    const bf16* __restrict__ Qu,   // [B*S][E]
    const bf16* __restrict__ Qv,   // [B*S][E]
    const bf16* __restrict__ Kb,   // [B*KLEN][E]
    const bf16* __restrict__ Vt,   // [B][E][KLEN]
    const bf16* __restrict__ Rb,   // [KLEN][E]
    bf16* __restrict__ O)          // [B*S][E]
{
    const int qphys = blockIdx.x, h = blockIdx.y, b = blockIdx.z;
    // pair long and short blocks: (0,7),(1,6),(2,5),(3,4) -> equal 25-tile pairs
    const int qt = (qphys & 1) ? (7 - (qphys >> 1)) : (qphys >> 1);
    const int q0 = qt * FQ;
    const int t = threadIdx.x;
    const int w = t >> 6, lane = t & 63;
    const int fr = lane & 15, quad = lane >> 4;
    const int qbase = q0 + w * 16;

    __shared__ short Ks[FK][72];
    __shared__ short Vs[64][72];       // [d][k]
    __shared__ short Rs[128][72];      // circular R band, slot = j & 127
    __shared__ short BDs[4][80][20];   // per-wave BD transposed [jlr][qw]
    __shared__ short Ps[4][16][72];    // per-wave P

    // Q A-frags straight from global (one-time)
    const short* quptr = (const short*)Qu + ((size_t)(b * S + qbase + fr)) * E + h * DH + quad * 8;
    const frag_ab au0 = *(const frag_ab*)(quptr);
    const frag_ab au1 = *(const frag_ab*)(quptr + 32);
    const short* qvptr = (const short*)Qv + ((size_t)(b * S + qbase + fr)) * E + h * DH + quad * 8;
    const frag_ab av0 = *(const frag_ab*)(qvptr);
    const frag_ab av1 = *(const frag_ab*)(qvptr + 32);

    frag_cd accO[4];
    #pragma unroll
    for (int i = 0; i < 4; ++i) accO[i] = (frag_cd)(0.0f);
    float mrow[4] = {-3.0e38f, -3.0e38f, -3.0e38f, -3.0e38f};
    float lrow[4] = {0.f, 0.f, 0.f, 0.f};

    const int srow = t >> 2, scol = (t & 3) * 16;   // K/V staging
    const short* kg = (const short*)Kb + ((size_t)(b * KLEN + srow)) * E + h * DH + scol;
    const short* vg = (const short*)Vt + ((size_t)(b * E + h * DH + srow)) * KLEN + scol;
    const int ntb0 = 3 - w;            // wave BD window: n-tiles ntb0..ntb0+4
    const int b0 = 448 - q0;           // R band origin at kt=0 (0..448)

    // ---- initial R window: rows j = b0 .. b0+127 (always <= 575, no clamp) --
    {
        const int rr = t >> 1, rc = (t & 1) * 32;
        const int j = b0 + rr;
        const int slot = j & 127;
        const short* rp = (const short*)Rb + (size_t)j * E + h * DH + rc;
        *(uint4*)&Rs[slot][rc]      = *(const uint4*)(rp);
        *(uint4*)&Rs[slot][rc + 8]  = *(const uint4*)(rp + 8);
        *(uint4*)&Rs[slot][rc + 16] = *(const uint4*)(rp + 16);
        *(uint4*)&Rs[slot][rc + 24] = *(const uint4*)(rp + 24);
    }

    const int ntiles = 9 + qt;
    for (int kt = 0; kt < ntiles; ++kt) {
        const int k0 = kt * FK;
        __syncthreads();
        {   // stage K[64k][64d] and V^T[64d][64k]
            const short* kp = kg + (size_t)k0 * E;
            *(uint4*)&Ks[srow][scol]     = *(const uint4*)(kp);
            *(uint4*)&Ks[srow][scol + 8] = *(const uint4*)(kp + 8);
            const short* vp = vg + k0;
            *(uint4*)&Vs[srow][scol]     = *(const uint4*)(vp);
            *(uint4*)&Vs[srow][scol + 8] = *(const uint4*)(vp + 8);
        }
        if (kt >= 1) {   // slide R window: load 64 new rows
            const int r64 = t >> 2, rc = (t & 3) * 16;
            int j = b0 + 64 * kt + 64 + r64;
            const int slot = j & 127;
            if (j > KLEN - 1) j = KLEN - 1;   // clamped rows feed masked scores only
            const short* rp = (const short*)Rb + (size_t)j * E + h * DH + rc;
            *(uint4*)&Rs[slot][rc]     = *(const uint4*)(rp);
            *(uint4*)&Rs[slot][rc + 8] = *(const uint4*)(rp + 8);
        }
        __syncthreads();

        const int roff = (b0 + 64 * kt) & 127;   // band start slot

        // ---- BD tile: BDs[w][jlr][qw] = Qv·R_band^T (wave's 80-col window) --
        #pragma unroll
        for (int i = 0; i < 5; ++i) {
            const int ntb = ntb0 + i;
            const int slot = (roff + ntb * 16 + fr) & 127;
            const frag_ab rf0 = *(const frag_ab*)&Rs[slot][quad * 8];
            const frag_ab rf1 = *(const frag_ab*)&Rs[slot][32 + quad * 8];
            frag_cd z = (frag_cd)(0.0f);
            z = __builtin_amdgcn_mfma_f32_16x16x32_bf16(av0, rf0, z, 0, 0, 0);
            z = __builtin_amdgcn_mfma_f32_16x16x32_bf16(av1, rf1, z, 0, 0, 0);
            union { uint2 u; unsigned short sh[4]; } pk;
            pk.sh[0] = f2bs(z[0]); pk.sh[1] = f2bs(z[1]);
            pk.sh[2] = f2bs(z[2]); pk.sh[3] = f2bs(z[3]);
            *(uint2*)&BDs[w][i * 16 + fr][quad * 4] = pk.u;
        }

        // ---- S = Qu·K^T ----
        frag_cd sc[4];
        #pragma unroll
        for (int nt = 0; nt < 4; ++nt) {
            const frag_ab kf0 = *(const frag_ab*)&Ks[nt * 16 + fr][quad * 8];
            const frag_ab kf1 = *(const frag_ab*)&Ks[nt * 16 + fr][32 + quad * 8];
            frag_cd z = (frag_cd)(0.0f);
            z = __builtin_amdgcn_mfma_f32_16x16x32_bf16(au0, kf0, z, 0, 0, 0);
            z = __builtin_amdgcn_mfma_f32_16x16x32_bf16(au1, kf1, z, 0, 0, 0);
            sc[nt] = z;
        }

        // ---- +BD (from LDS), mask, online softmax per C-row ----
        #pragma unroll
        for (int r = 0; r < 4; ++r) {
            const int qw = quad * 4 + r;
            const int qrow = qbase + qw;
            float sv[4];
            #pragma unroll
            for (int nt = 0; nt < 4; ++nt) {
                const int kcol = k0 + nt * 16 + fr;
                const int jlr = nt * 16 + fr + 15 - qw;   // 0..78
                const float bd = bs2f(BDs[w][jlr][qw]);
                const float sval = (sc[nt][r] + bd) * 0.125f;
                sv[nt] = (kcol <= MEM + qrow) ? sval : -1e30f;
            }
            float tm = fmaxf(fmaxf(sv[0], sv[1]), fmaxf(sv[2], sv[3]));
            tm = fmaxf(tm, __shfl_xor(tm, 1, 64));
            tm = fmaxf(tm, __shfl_xor(tm, 2, 64));
            tm = fmaxf(tm, __shfl_xor(tm, 4, 64));
            tm = fmaxf(tm, __shfl_xor(tm, 8, 64));
            const float mn = fmaxf(mrow[r], tm);
            const float p0 = __expf(sv[0] - mn), p1 = __expf(sv[1] - mn);
            const float p2 = __expf(sv[2] - mn), p3 = __expf(sv[3] - mn);
            float wsum = p0 + p1 + p2 + p3;
            wsum += __shfl_xor(wsum, 1, 64);
            wsum += __shfl_xor(wsum, 2, 64);
            wsum += __shfl_xor(wsum, 4, 64);
            wsum += __shfl_xor(wsum, 8, 64);
            const float al = __expf(mrow[r] - mn);
            lrow[r] = lrow[r] * al + wsum;
            mrow[r] = mn;
            #pragma unroll
            for (int nt = 0; nt < 4; ++nt) accO[nt][r] *= al;
            Ps[w][qw][fr]      = (short)f2bs(p0);
            Ps[w][qw][16 + fr] = (short)f2bs(p1);
            Ps[w][qw][32 + fr] = (short)f2bs(p2);
            Ps[w][qw][48 + fr] = (short)f2bs(p3);
        }

        // ---- O += P·V (per-wave P; same-wave LDS, DS in-order) ----
        const frag_ab pf0 = *(const frag_ab*)&Ps[w][fr][quad * 8];
        const frag_ab pf1 = *(const frag_ab*)&Ps[w][fr][32 + quad * 8];
        #pragma unroll
        for (int nt = 0; nt < 4; ++nt) {
            const frag_ab vf0 = *(const frag_ab*)&Vs[nt * 16 + fr][quad * 8];
            const frag_ab vf1 = *(const frag_ab*)&Vs[nt * 16 + fr][32 + quad * 8];
            accO[nt] = __builtin_amdgcn_mfma_f32_16x16x32_bf16(pf0, vf0, accO[nt], 0, 0, 0);
            accO[nt] = __builtin_amdgcn_mfma_f32_16x16x32_bf16(pf1, vf1, accO[nt], 0, 0, 0);
        }
    }

    #pragma unroll
    for (int r = 0; r < 4; ++r) {
        const float inv = 1.0f / lrow[r];
        bf16* po = O + ((size_t)(b * S + qbase + quad * 4 + r)) * E + h * DH + fr;
        #pragma unroll
        for (int nt = 0; nt < 4; ++nt)
            po[nt * 16] = __float2bfloat16(accO[nt][r] * inv);
    }
}

extern "C" void kernel_launch(void* const* d_in, const int* in_sizes, int n_in,
                              void* d_out, int out_size, void* d_ws, size_t ws_size,
                              hipStream_t stream)
{
    const float* obs  = (const float*)d_in[0];
    const float* mem  = (const float*)d_in[1];
    // d_in[2] = mask: deterministic (k <= MEM + q), recomputed in-kernel
    const float* Wenc = (const float*)d_in[3];
    const float* benc = (const float*)d_in[4];
    const float* ln1s = (const float*)d_in[5];
    const float* ln1b = (const float*)d_in[6];
    const float* Wq   = (const float*)d_in[7];
    const float* bq   = (const float*)d_in[8];
    const float* Wk   = (const float*)d_in[9];
    const float* bk   = (const float*)d_in[10];
    const float* Wv   = (const float*)d_in[11];
    const float* bv   = (const float*)d_in[12];
    const float* Wr   = (const float*)d_in[13];
    const float* ub   = (const float*)d_in[14];
    const float* vb   = (const float*)d_in[15];
    const float* Wo   = (const float*)d_in[16];
    const float* bo   = (const float*)d_in[17];
    const float* ln2s = (const float*)d_in[18];
    const float* ln2b = (const float*)d_in[19];
    const float* W1   = (const float*)d_in[20];
    const float* b1   = (const float*)d_in[21];
    const float* W2   = (const float*)d_in[22];
    const float* b2   = (const float*)d_in[23];

    // ---- workspace ----
    float* wsf = (float*)d_ws;
    float* X = wsf;                                   // fp32 [B*S*E]
    bf16* wsb = (bf16*)(wsf + (size_t)B * S * E);
    size_t ob = 0;
    bf16* OBSb = wsb + ob; ob += (size_t)B * S * OBS;
    bf16* QNb  = wsb + ob; ob += (size_t)B * S * E;
    bf16* PEb  = wsb + ob; ob += (size_t)KLEN * E;
    bf16* RBb  = wsb + ob; ob += (size_t)KLEN * E;
    bf16* WencT= wsb + ob; ob += (size_t)OBS * E;
    bf16* WqT  = wsb + ob; ob += (size_t)L * E * E;
    bf16* WkvT = wsb + ob; ob += (size_t)L * 2 * E * E;   // [L][1024][512]
    bf16* WrT  = wsb + ob; ob += (size_t)L * E * E;
    bf16* WoT  = wsb + ob; ob += (size_t)L * E * E;
    bf16* W1T  = wsb + ob; ob += (size_t)L * E * E;
    bf16* W2T  = wsb + ob; ob += (size_t)L * E * E;
    bf16* QUb  = wsb + ob; ob += (size_t)B * S * E;
    bf16* QVb  = wsb + ob; ob += (size_t)B * S * E;
    bf16* KBb  = wsb + ob; ob += (size_t)B * KLEN * E;
    bf16* VTb  = wsb + ob; ob += (size_t)B * E * KLEN;
    bf16* OBb  = wsb + ob; ob += (size_t)B * S * E;
    // union: {VKb, VBb} ∪ {HB, FFb} (disjoint lifetimes per layer)
    char* uni = (char*)(wsb + ob);
    bf16*  VKb = (bf16*)uni;                          // [B*KLEN][E] (8 MB) @0
    bf16*  VBb = (bf16*)(uni + ((size_t)8 << 20));    // [B*KLEN][E] (8 MB) @8M
    float* HB  = (float*)uni;                         // [B*S][E] fp32 (8 MB) @0
    bf16*  FFb = (bf16*)(uni + ((size_t)8 << 20));    // [B*S][E] (4 MB) @8M

    // ---- setup: merged weight transposes, obs cast + pe ----
    transpose_all_kernel<<<dim3(E / 32, E / 32, 29), 256, 0, stream>>>(
        Wq, Wk, Wv, Wr, Wo, W1, W2, Wenc, WqT, WkvT, WrT, WoT, W1T, W2T, WencT);
    setup_kernel<<<(B * S * OBS + KLEN * E) / 256, 256, 0, stream>>>(obs, OBSb, PEb);

    // encoder: X = obs @ W_enc + b_enc (fp32)
    mfma_gemm_kernel<<<dim3(E / 64, (B * S) / 128), 256, 0, stream>>>(
        OBSb, WencT, benc, nullptr, X, nullptr, OBS, E, 0);

    for (int li = 0; li < L; ++li) {
        const size_t wOff = (size_t)li * E * E;
        const size_t vOff = (size_t)li * E;

        ln1_kernel<<<2 * B * S, 256, 0, stream>>>(
            mem, X, li, ln1s + vOff, ln1b + vOff, QNb, VKb);

        qkvr_kernel<<<1344, 256, 0, stream>>>(
            QNb, VKb, PEb, WqT + wOff, WkvT + (size_t)li * 2 * E * E, WrT + wOff,
            bq + vOff, ub + vOff, vb + vOff, bk + vOff, bv + vOff,
            QUb, QVb, KBb, VBb, RBb);

        transpose_v_kernel<<<dim3(KLEN / 64, E / 64, B), 256, 0, stream>>>(VBb, VTb);

        mfma_flash_kernel<<<dim3(S / FQ, H, B), 256, 0, stream>>>(
            QUb, QVb, KBb, VTb, RBb, OBb);

        // HB = X + (O @ Wo + bo)
        mfma_gemm_kernel<<<dim3(E / 64, (B * S) / 128), 256, 0, stream>>>(
            OBb, WoT + wOff, bo + vOff, X, HB, nullptr, E, E, 0);
        ln_f32_kernel<<<B * S, 256, 0, stream>>>(HB, ln2s + vOff, ln2b + vOff, QNb);
        // FFb = gelu(hn @ W1 + b1)
        mfma_gemm_kernel<<<dim3(E / 64, (B * S) / 128), 256, 0, stream>>>(
            QNb, W1T + wOff, b1 + vOff, nullptr, nullptr, FFb, E, E, 1);
        // X = FF @ W2 + b2 + HB
        mfma_gemm_kernel<<<dim3(E / 64, (B * S) / 128), 256, 0, stream>>>(
            FFb, W2T + wOff, b2 + vOff, HB, X, nullptr, E, E, 0);
    }

    hipMemcpyAsync(d_out, X, (size_t)B * S * E * sizeof(float),
                   hipMemcpyDeviceToDevice, stream);
}